// Round 7
// baseline (60.887 us; speedup 1.0000x reference)
//
#include <hip/hip_runtime.h>
#include <math.h>

#pragma clang fp contract(off)

#define NPIX 1024

// ---------------------------------------------------------------------------
// 9-tap gaussian (sigma=1, lw=4): phi in f64, normalized with numpy's pairwise
// sum order, cast to f32 — matches jnp.asarray(GAUSS_K, float32).
// ---------------------------------------------------------------------------
__device__ __forceinline__ void compute_gk(float gk[9]) {
    double phi[9];
    #pragma unroll
    for (int t = 0; t < 9; ++t) {
        double d = (double)(t - 4);
        phi[t] = exp(-0.5 * d * d);
    }
    double s = (((phi[0] + phi[1]) + (phi[2] + phi[3])) +
                ((phi[4] + phi[5]) + (phi[6] + phi[7]))) + phi[8];
    #pragma unroll
    for (int t = 0; t < 9; ++t) gk[t] = (float)(phi[t] / s);
}

__device__ __forceinline__ float ldz(const float* b, int i, int j) {
    return (i >= 0 && i < 32 && j >= 0 && j < 32) ? b[(i << 5) + j] : 0.0f;
}
__device__ __forceinline__ float ldc(const float* b, int i, int j) {
    i = i < 0 ? 0 : (i > 31 ? 31 : i);
    j = j < 0 ? 0 : (j > 31 ? 31 : j);
    return b[(i << 5) + j];
}

// ---------------------------------------------------------------------------
// Kernel A (1 block): gk -> ws_gk; bleed+1e-12 -> ws_bleed;
// er = erode3x3(mask!=0) & (mag2(batch0) > 0) -> ws_er.  (round-3/5 proven)
// ---------------------------------------------------------------------------
__global__ __launch_bounds__(256) void canny_pre(const float* __restrict__ x,
                                                 const float* __restrict__ mask,
                                                 float* __restrict__ ws_bleed,
                                                 unsigned int* __restrict__ ws_er,
                                                 float* __restrict__ ws_gk) {
    __shared__ float A[NPIX], Bf[NPIX], C[NPIX], D[NPIX], BL[NPIX];
    __shared__ unsigned int er32[32];
    const int tid = threadIdx.x;
    float gk[9];
    compute_gk(gk);
    if (tid < 9) ws_gk[tid] = gk[tid];

    #pragma unroll
    for (int k = 0; k < 4; ++k) { int p = tid + (k << 8); A[p] = mask[p]; }
    if (tid < 32) er32[tid] = 0u;
    __syncthreads();

    #pragma unroll
    for (int k = 0; k < 4; ++k) {
        int p = tid + (k << 8), i = p >> 5, j = p & 31;
        float s = 0.0f;
        #pragma unroll
        for (int t = 0; t < 9; ++t) s = __fmaf_rn(gk[t], ldz(A, i + t - 4, j), s);
        Bf[p] = s;
    }
    __syncthreads();
    #pragma unroll
    for (int k = 0; k < 4; ++k) {
        int p = tid + (k << 8), i = p >> 5, j = p & 31;
        float s = 0.0f;
        #pragma unroll
        for (int t = 0; t < 9; ++t) s = __fmaf_rn(gk[t], ldz(Bf, i, j + t - 4), s);
        BL[p] = s;
        ws_bleed[p] = s + 1e-12f;   // main divides by exactly this value
    }

    bool er2d[4];
    #pragma unroll
    for (int k = 0; k < 4; ++k) {
        int p = tid + (k << 8), i = p >> 5, j = p & 31;
        bool e = true;
        for (int di = -1; di <= 1; ++di)
            for (int dj = -1; dj <= 1; ++dj) {
                int ii = i + di, jj = j + dj;
                e = e && (ii >= 0 && ii < 32 && jj >= 0 && jj < 32) && (A[(ii << 5) + jj] != 0.0f);
            }
        er2d[k] = e;
    }
    __syncthreads();

    #pragma unroll
    for (int k = 0; k < 4; ++k) {
        int p = tid + (k << 8);
        float r = x[p]            * 0.5f + 0.5f;
        float g = x[p + NPIX]     * 0.5f + 0.5f;
        float b = x[p + 2 * NPIX] * 0.5f + 0.5f;
        A[p] = r * 0.299f + g * 0.587f + b * 0.114f;
    }
    __syncthreads();
    #pragma unroll
    for (int k = 0; k < 4; ++k) {
        int p = tid + (k << 8), i = p >> 5, j = p & 31;
        float s = 0.0f;
        #pragma unroll
        for (int t = 0; t < 9; ++t) s = __fmaf_rn(gk[t], ldz(A, i + t - 4, j), s);
        Bf[p] = s;
    }
    __syncthreads();
    #pragma unroll
    for (int k = 0; k < 4; ++k) {
        int p = tid + (k << 8), i = p >> 5, j = p & 31;
        float s = 0.0f;
        #pragma unroll
        for (int t = 0; t < 9; ++t) s = __fmaf_rn(gk[t], ldz(Bf, i, j + t - 4), s);
        A[p] = s;
    }
    __syncthreads();
    #pragma unroll
    for (int k = 0; k < 4; ++k) { int p = tid + (k << 8); A[p] = A[p] / (BL[p] + 1e-12f); }
    __syncthreads();
    #pragma unroll
    for (int k = 0; k < 4; ++k) { int p = tid + (k << 8), i = p >> 5, j = p & 31;
        Bf[p] = ldc(A, i, j + 1) - ldc(A, i, j - 1); }
    __syncthreads();
    #pragma unroll
    for (int k = 0; k < 4; ++k) { int p = tid + (k << 8), i = p >> 5, j = p & 31;
        C[p] = (ldc(Bf, i - 1, j) + 2.0f * ldc(Bf, i, j)) + ldc(Bf, i + 1, j); }
    __syncthreads();
    #pragma unroll
    for (int k = 0; k < 4; ++k) { int p = tid + (k << 8), i = p >> 5, j = p & 31;
        Bf[p] = ldc(A, i + 1, j) - ldc(A, i - 1, j); }
    __syncthreads();
    #pragma unroll
    for (int k = 0; k < 4; ++k) { int p = tid + (k << 8), i = p >> 5, j = p & 31;
        D[p] = (ldc(Bf, i, j - 1) + 2.0f * ldc(Bf, i, j)) + ldc(Bf, i, j + 1); }
    __syncthreads();
    #pragma unroll
    for (int k = 0; k < 4; ++k) {
        int p = tid + (k << 8), i = p >> 5, j = p & 31;
        if (er2d[k]) {
            float m2 = D[p] * D[p] + C[p] * C[p];
            if (m2 > 0.0f) atomicOr(&er32[i], 1u << j);
        }
    }
    __syncthreads();
    if (tid < 32) ws_er[tid] = er32[tid];
}

// ---------------------------------------------------------------------------
// Kernel B: ONE WAVE per image, 4 waves/block, ZERO __syncthreads.
// Wave-private LDS: A = 40x32 (gray+guards, later sm, later 34x34 mag tile),
// B = 32x40 (blurH+guard cols). 16 px/lane. Masks/flood all in registers via
// ballot/shfl. Compiler fences only (waves are lockstep; DS ops in-order).
// ---------------------------------------------------------------------------
__global__ __launch_bounds__(256) void canny_main4(const float* __restrict__ x,
                                                   const float* __restrict__ ws_bleed,
                                                   const unsigned int* __restrict__ ws_er,
                                                   const float* __restrict__ ws_gk,
                                                   float* __restrict__ out, int Bn) {
    __shared__ float lds[4][2560];          // 40 KB/block -> 4 blocks/CU
    const int tid = threadIdx.x;
    const int l = tid & 63;
    const int w = tid >> 6;
    int b = blockIdx.x * 4 + w;
    if (b >= Bn) b = Bn - 1;                // tail guard (Bn%4==0 in practice)
    float* A  = lds[w];                     // 1280 floats
    float* Bq = lds[w] + 1280;              // 1280 floats

    float gk[9];
    #pragma unroll
    for (int t = 0; t < 9; ++t) gk[t] = ws_gk[t];
    unsigned int er_reg = ws_er[l & 31];    // lane r holds er row (r&31)
    float blv[16];
    #pragma unroll
    for (int k = 0; k < 16; ++k) blv[k] = ws_bleed[l + (k << 6)];

    // ---- phase 1: zero guards, gray -> A interior (rows 4..35) ----
    {
        float4* A4 = (float4*)A;
        float4* B4 = (float4*)Bq;
        const float4 z4 = make_float4(0.0f, 0.0f, 0.0f, 0.0f);
        if (l < 32) A4[l] = z4; else A4[288 + (l - 32)] = z4;      // rows 0-3, 36-39
        { int r = l >> 1, side = l & 1; B4[10 * r + 9 * side] = z4; } // cols 0-3, 36-39
        const float4* xr = (const float4*)(x + (size_t)b * 3 * NPIX);
        #pragma unroll
        for (int k = 0; k < 4; ++k) {
            int f = l + (k << 6);
            float4 r4 = xr[f], g4 = xr[f + 256], c4 = xr[f + 512];
            float4 gy;
            gy.x = (r4.x * 0.5f + 0.5f) * 0.299f + (g4.x * 0.5f + 0.5f) * 0.587f + (c4.x * 0.5f + 0.5f) * 0.114f;
            gy.y = (r4.y * 0.5f + 0.5f) * 0.299f + (g4.y * 0.5f + 0.5f) * 0.587f + (c4.y * 0.5f + 0.5f) * 0.114f;
            gy.z = (r4.z * 0.5f + 0.5f) * 0.299f + (g4.z * 0.5f + 0.5f) * 0.587f + (c4.z * 0.5f + 0.5f) * 0.114f;
            gy.w = (r4.w * 0.5f + 0.5f) * 0.299f + (g4.w * 0.5f + 0.5f) * 0.587f + (c4.w * 0.5f + 0.5f) * 0.114f;
            A4[((f >> 3) + 4) * 8 + (f & 7)] = gy;
        }
    }
    asm volatile("" ::: "memory");

    // ---- phase 2: blur along H: A (guarded) -> B interior cols 4..35 ----
    #pragma unroll
    for (int k = 0; k < 16; ++k) {
        int p = l + (k << 6), i = p >> 5, j = p & 31;
        float s = 0.0f;
        #pragma unroll
        for (int t = 0; t < 9; ++t) s = __fmaf_rn(gk[t], A[((i + t) << 5) + j], s);
        Bq[i * 40 + j + 4] = s;
    }
    asm volatile("" ::: "memory");

    // ---- phase 3: blur along W + divide: B (guarded) -> sm -> A interior ----
    #pragma unroll
    for (int k = 0; k < 16; ++k) {
        int p = l + (k << 6), i = p >> 5, j = p & 31;
        float s = 0.0f;
        #pragma unroll
        for (int t = 0; t < 9; ++t) s = __fmaf_rn(gk[t], Bq[i * 40 + j + t], s);
        A[((i + 4) << 5) + j] = s / blv[k];
    }
    asm volatile("" ::: "memory");

    // ---- phase 4: fused sobel + mag (regs), sm read from A interior ----
    float jsr[16], isr[16], mr[16];
    {
        const float* S = A + 128;           // S[(i<<5)+j] == sm(i,j)
        #pragma unroll
        for (int k = 0; k < 16; ++k) {
            int p = l + (k << 6), i = p >> 5, j = p & 31;
            int im1 = i > 0 ? i - 1 : 0, ip1 = i < 31 ? i + 1 : 31;
            int jm1 = j > 0 ? j - 1 : 0, jp1 = j < 31 ? j + 1 : 31;
            float smm = S[(im1 << 5) + jm1], sm0 = S[(im1 << 5) + j], smp = S[(im1 << 5) + jp1];
            float s0m = S[(i   << 5) + jm1],                          s0p = S[(i   << 5) + jp1];
            float spm = S[(ip1 << 5) + jm1], sp0 = S[(ip1 << 5) + j], spp = S[(ip1 << 5) + jp1];
            float tm = smp - smm, t0 = s0p - s0m, tp = spp - spm;
            float jsob = (tm + 2.0f * t0) + tp;
            float um = spm - smm, u0 = sp0 - sm0, up = spp - smp;
            float isob = (um + 2.0f * u0) + up;
            jsr[k] = jsob; isr[k] = isob;
            mr[k] = sqrtf((isob * isob + jsob * jsob) + 1e-9f);
        }
    }
    asm volatile("" ::: "memory");

    // ---- phase 5: A becomes 34x34 mag tile: zero guard ring, write mags ----
    #pragma unroll
    for (int t = 0; t < 3; ++t) {
        int q = l + (t << 6);
        if (q < 132) {
            int idx;
            if (q < 34)       idx = q;                    // row 0
            else if (q < 68)  idx = 33 * 34 + (q - 34);   // row 33
            else if (q < 100) idx = (q - 67) * 34;        // col 0, rows 1..32
            else              idx = (q - 99) * 34 + 33;   // col 33, rows 1..32
            A[idx] = 0.0f;
        }
    }
    #pragma unroll
    for (int k = 0; k < 16; ++k) {
        int p = l + (k << 6), i = p >> 5, j = p & 31;
        A[(i + 1) * 34 + (j + 1)] = mr[k];
    }
    asm volatile("" ::: "memory");

    // ---- phase 6: branchless NMS; ballots -> per-lane row masks ----
    unsigned int myhi = 0u, mylo = 0u;
    #pragma unroll
    for (int k = 0; k < 16; ++k) {
        int p = l + (k << 6), i = p >> 5, j = p & 31;
        float iv = isr[k], jv = jsr[k], m = mr[k];
        float ai = fabsf(iv), aj = fabsf(jv);
        bool same = (iv >= 0.0f && jv >= 0.0f) || (iv <= 0.0f && jv <= 0.0f);
        bool opp  = (iv <= 0.0f && jv >= 0.0f) || (iv >= 0.0f && jv <= 0.0f);
        bool age  = (ai >= aj), ale = (ai <= aj);
        int oct = (opp && age) ? 3 : (opp && ale) ? 2 : (same && ale) ? 1 : 0;
        float ais = ai > 0.0f ? ai : 1.0f;
        float ajs = aj > 0.0f ? aj : 1.0f;
        float num = (oct == 3 || oct == 0) ? aj : ai;
        float den = (oct == 3) ? ais : (oct == 0) ? (ai + 1e-9f) : ajs;
        float wq = num / den;
        float omw = 1.0f - wq;
        int p2i = (oct >= 2) ? -1 : 1;
        int p1i = (oct == 0) ? 1 : (oct == 3) ? -1 : 0;
        int p1j = (oct == 1 || oct == 2) ? 1 : 0;
        int base = (i + 1) * 34 + (j + 1);
        float ip = A[base + p2i * 34 + 1] * wq + A[base + p1i * 34 + p1j] * omw;
        float im = A[base - p2i * 34 - 1] * wq + A[base - p1i * 34 - p1j] * omw;
        bool lm = (ip <= m) && (im <= m);
        unsigned int ew = (unsigned int)__shfl((int)er_reg, (k << 1) + (l >> 5), 64);
        bool eb = (ew >> (l & 31)) & 1u;
        unsigned long long bh = __ballot(lm && eb && (m >= 0.2f));
        unsigned long long bl = __ballot(lm && eb && (m >= 0.1f));
        if (l < 32 && (l >> 1) == k) {      // lane r holds row r (made at k=r>>1)
            myhi = (l & 1) ? (unsigned int)(bh >> 32) : (unsigned int)bh;
            mylo = (l & 1) ? (unsigned int)(bl >> 32) : (unsigned int)bl;
        }
    }

    // ---- phase 7: hysteresis flood, all-register (lanes 0..31 = rows) ----
    unsigned int cur = myhi;
    {
        const unsigned int lw = mylo;       // lanes >=32: 0 -> inert
        for (;;) {
            unsigned int sp  = cur | (cur << 1) | (cur >> 1);
            unsigned int up  = (unsigned int)__shfl((int)sp, (l + 63) & 63, 64);
            if ((l & 31) == 0) up = 0u;
            unsigned int dn  = (unsigned int)__shfl((int)sp, (l + 1) & 63, 64);
            if ((l & 31) == 31) dn = 0u;
            unsigned int nxt = (sp | up | dn) & lw;
            bool ch = (nxt != cur);
            cur = nxt;
            if (__ballot((int)ch) == 0ull) break;
        }
    }

    // ---- phase 8: store via shfl of row words ----
    {
        float4* o4 = (float4*)(out + (size_t)b * NPIX);
        #pragma unroll
        for (int k = 0; k < 4; ++k) {
            int f = l + (k << 6);
            unsigned int wd = (unsigned int)__shfl((int)cur, f >> 3, 64);
            int j0 = (f & 7) << 2;
            float4 o;
            o.x = ((wd >> (j0    )) & 1u) ? 1.0f : -1.0f;
            o.y = ((wd >> (j0 + 1)) & 1u) ? 1.0f : -1.0f;
            o.z = ((wd >> (j0 + 2)) & 1u) ? 1.0f : -1.0f;
            o.w = ((wd >> (j0 + 3)) & 1u) ? 1.0f : -1.0f;
            o4[f] = o;
        }
    }
}

extern "C" void kernel_launch(void* const* d_in, const int* in_sizes, int n_in,
                              void* d_out, int out_size, void* d_ws, size_t ws_size,
                              hipStream_t stream) {
    const float* x    = (const float*)d_in[0];
    const float* mask = (const float*)d_in[1];
    float* out        = (float*)d_out;
    float* ws_bleed   = (float*)d_ws;
    unsigned int* ws_er = (unsigned int*)(ws_bleed + NPIX);
    float* ws_gk      = (float*)(ws_er + 32);
    int Bn = in_sizes[0] / (3 * NPIX);

    hipLaunchKernelGGL(canny_pre, dim3(1), dim3(256), 0, stream, x, mask, ws_bleed, ws_er, ws_gk);
    hipLaunchKernelGGL(canny_main4, dim3((Bn + 3) / 4), dim3(256), 0, stream,
                       x, ws_bleed, ws_er, ws_gk, out, Bn);
}

// Round 8
// 52.706 us; speedup vs baseline: 1.1552x; 1.1552x over previous
//
#include <hip/hip_runtime.h>
#include <math.h>

#pragma clang fp contract(off)

#define NPIX 1024

// ---------------------------------------------------------------------------
// 9-tap gaussian (sigma=1, lw=4): phi in f64, normalized with numpy's pairwise
// sum order, cast to f32 — matches jnp.asarray(GAUSS_K, float32).
// ---------------------------------------------------------------------------
__device__ __forceinline__ void compute_gk(float gk[9]) {
    double phi[9];
    #pragma unroll
    for (int t = 0; t < 9; ++t) {
        double d = (double)(t - 4);
        phi[t] = exp(-0.5 * d * d);
    }
    double s = (((phi[0] + phi[1]) + (phi[2] + phi[3])) +
                ((phi[4] + phi[5]) + (phi[6] + phi[7]))) + phi[8];
    #pragma unroll
    for (int t = 0; t < 9; ++t) gk[t] = (float)(phi[t] / s);
}

__device__ __forceinline__ float ldz(const float* b, int i, int j) {
    return (i >= 0 && i < 32 && j >= 0 && j < 32) ? b[(i << 5) + j] : 0.0f;
}
__device__ __forceinline__ float ldc(const float* b, int i, int j) {
    i = i < 0 ? 0 : (i > 31 ? 31 : i);
    j = j < 0 ? 0 : (j > 31 ? 31 : j);
    return b[(i << 5) + j];
}

// ---------------------------------------------------------------------------
// Kernel A (1 block): gk -> ws_gk; bleed+1e-12 -> ws_bleed;
// er = erode3x3(mask!=0) & (mag2(batch0) > 0) -> ws_er.  (round-3/5 proven)
// ---------------------------------------------------------------------------
__global__ __launch_bounds__(256) void canny_pre(const float* __restrict__ x,
                                                 const float* __restrict__ mask,
                                                 float* __restrict__ ws_bleed,
                                                 unsigned int* __restrict__ ws_er,
                                                 float* __restrict__ ws_gk) {
    __shared__ float A[NPIX], Bf[NPIX], C[NPIX], D[NPIX], BL[NPIX];
    __shared__ unsigned int er32[32];
    const int tid = threadIdx.x;
    float gk[9];
    compute_gk(gk);
    if (tid < 9) ws_gk[tid] = gk[tid];

    #pragma unroll
    for (int k = 0; k < 4; ++k) { int p = tid + (k << 8); A[p] = mask[p]; }
    if (tid < 32) er32[tid] = 0u;
    __syncthreads();

    #pragma unroll
    for (int k = 0; k < 4; ++k) {
        int p = tid + (k << 8), i = p >> 5, j = p & 31;
        float s = 0.0f;
        #pragma unroll
        for (int t = 0; t < 9; ++t) s = __fmaf_rn(gk[t], ldz(A, i + t - 4, j), s);
        Bf[p] = s;
    }
    __syncthreads();
    #pragma unroll
    for (int k = 0; k < 4; ++k) {
        int p = tid + (k << 8), i = p >> 5, j = p & 31;
        float s = 0.0f;
        #pragma unroll
        for (int t = 0; t < 9; ++t) s = __fmaf_rn(gk[t], ldz(Bf, i, j + t - 4), s);
        BL[p] = s;
        ws_bleed[p] = s + 1e-12f;   // main divides by exactly this value
    }

    bool er2d[4];
    #pragma unroll
    for (int k = 0; k < 4; ++k) {
        int p = tid + (k << 8), i = p >> 5, j = p & 31;
        bool e = true;
        for (int di = -1; di <= 1; ++di)
            for (int dj = -1; dj <= 1; ++dj) {
                int ii = i + di, jj = j + dj;
                e = e && (ii >= 0 && ii < 32 && jj >= 0 && jj < 32) && (A[(ii << 5) + jj] != 0.0f);
            }
        er2d[k] = e;
    }
    __syncthreads();

    #pragma unroll
    for (int k = 0; k < 4; ++k) {
        int p = tid + (k << 8);
        float r = x[p]            * 0.5f + 0.5f;
        float g = x[p + NPIX]     * 0.5f + 0.5f;
        float b = x[p + 2 * NPIX] * 0.5f + 0.5f;
        A[p] = r * 0.299f + g * 0.587f + b * 0.114f;
    }
    __syncthreads();
    #pragma unroll
    for (int k = 0; k < 4; ++k) {
        int p = tid + (k << 8), i = p >> 5, j = p & 31;
        float s = 0.0f;
        #pragma unroll
        for (int t = 0; t < 9; ++t) s = __fmaf_rn(gk[t], ldz(A, i + t - 4, j), s);
        Bf[p] = s;
    }
    __syncthreads();
    #pragma unroll
    for (int k = 0; k < 4; ++k) {
        int p = tid + (k << 8), i = p >> 5, j = p & 31;
        float s = 0.0f;
        #pragma unroll
        for (int t = 0; t < 9; ++t) s = __fmaf_rn(gk[t], ldz(Bf, i, j + t - 4), s);
        A[p] = s;
    }
    __syncthreads();
    #pragma unroll
    for (int k = 0; k < 4; ++k) { int p = tid + (k << 8); A[p] = A[p] / (BL[p] + 1e-12f); }
    __syncthreads();
    #pragma unroll
    for (int k = 0; k < 4; ++k) { int p = tid + (k << 8), i = p >> 5, j = p & 31;
        Bf[p] = ldc(A, i, j + 1) - ldc(A, i, j - 1); }
    __syncthreads();
    #pragma unroll
    for (int k = 0; k < 4; ++k) { int p = tid + (k << 8), i = p >> 5, j = p & 31;
        C[p] = (ldc(Bf, i - 1, j) + 2.0f * ldc(Bf, i, j)) + ldc(Bf, i + 1, j); }
    __syncthreads();
    #pragma unroll
    for (int k = 0; k < 4; ++k) { int p = tid + (k << 8), i = p >> 5, j = p & 31;
        Bf[p] = ldc(A, i + 1, j) - ldc(A, i - 1, j); }
    __syncthreads();
    #pragma unroll
    for (int k = 0; k < 4; ++k) { int p = tid + (k << 8), i = p >> 5, j = p & 31;
        D[p] = (ldc(Bf, i, j - 1) + 2.0f * ldc(Bf, i, j)) + ldc(Bf, i, j + 1); }
    __syncthreads();
    #pragma unroll
    for (int k = 0; k < 4; ++k) {
        int p = tid + (k << 8), i = p >> 5, j = p & 31;
        if (er2d[k]) {
            float m2 = D[p] * D[p] + C[p] * C[p];
            if (m2 > 0.0f) atomicOr(&er32[i], 1u << j);
        }
    }
    __syncthreads();
    if (tid < 32) ws_er[tid] = er32[tid];
}

// ---------------------------------------------------------------------------
// Kernel B: one block per image, round-5 structure (6 barriers, 15.9 KB LDS)
// but each thread owns 4 CONSECUTIVE pixels (row i, cols j0..j0+3):
// addressing computed once, blur reads via ds_read_b128, sobel via b128 +
// uniform selects, masks via nibble + shfl_xor OR (no ballots, no atomics).
// ---------------------------------------------------------------------------
__global__ __launch_bounds__(256) void canny_main(const float* __restrict__ x,
                                                  const float* __restrict__ ws_bleed,
                                                  const unsigned int* __restrict__ ws_er,
                                                  const float* __restrict__ ws_gk,
                                                  float* __restrict__ out) {
    __shared__ float APAD[40 * 32];    // (i+4)*32 + j ; rows 0-3,36-39 zero
    __shared__ float BPAD[32 * 40];    // i*40 + (j+4) ; cols 0-3,36-39 zero
    __shared__ float MPAD[34 * 34];    // (i+1)*34 + (j+1) ; ring zero
    __shared__ unsigned int er[32], hi32[32], lo32[32], fin32[32];
    const int tid = threadIdx.x;
    const int b = blockIdx.x;
    const int i  = tid >> 3;           // row 0..31
    const int j0 = (tid & 7) << 2;     // col base 0,4,...,28

    float gk[9];
    #pragma unroll
    for (int t = 0; t < 9; ++t) gk[t] = ws_gk[t];

    // zero guards
    APAD[tid < 128 ? tid : 1024 + tid] = 0.0f;
    { int r = tid >> 3, c8 = tid & 7; BPAD[r * 40 + c8 + (c8 < 4 ? 0 : 32)] = 0.0f; }
    #pragma unroll
    for (int t = 0; t < 5; ++t) { int idx = tid + (t << 8); if (idx < 34 * 34) MPAD[idx] = 0.0f; }
    if (tid < 32) er[tid] = ws_er[tid];

    // ---- gray: float4 channel loads; px p = 4*tid.. = (i, j0..j0+3) ----
    {
        const float4* xr = (const float4*)(x + (size_t)b * 3 * NPIX);
        float4 r4 = xr[tid], g4 = xr[tid + 256], c4 = xr[tid + 512];
        float4 gy;
        gy.x = (r4.x * 0.5f + 0.5f) * 0.299f + (g4.x * 0.5f + 0.5f) * 0.587f + (c4.x * 0.5f + 0.5f) * 0.114f;
        gy.y = (r4.y * 0.5f + 0.5f) * 0.299f + (g4.y * 0.5f + 0.5f) * 0.587f + (c4.y * 0.5f + 0.5f) * 0.114f;
        gy.z = (r4.z * 0.5f + 0.5f) * 0.299f + (g4.z * 0.5f + 0.5f) * 0.587f + (c4.z * 0.5f + 0.5f) * 0.114f;
        gy.w = (r4.w * 0.5f + 0.5f) * 0.299f + (g4.w * 0.5f + 0.5f) * 0.587f + (c4.w * 0.5f + 0.5f) * 0.114f;
        *(float4*)&APAD[((i + 4) << 5) + j0] = gy;
    }
    __syncthreads();

    // ---- blur H (over rows): 9x b128 reads, FMA chain t ascending ----
    {
        float4 acc = make_float4(0.0f, 0.0f, 0.0f, 0.0f);
        #pragma unroll
        for (int t = 0; t < 9; ++t) {
            float4 v = *(const float4*)&APAD[((i + t) << 5) + j0];
            acc.x = __fmaf_rn(gk[t], v.x, acc.x);
            acc.y = __fmaf_rn(gk[t], v.y, acc.y);
            acc.z = __fmaf_rn(gk[t], v.z, acc.z);
            acc.w = __fmaf_rn(gk[t], v.w, acc.w);
        }
        *(float4*)&BPAD[i * 40 + j0 + 4] = acc;
    }
    __syncthreads();

    // ---- blur W (over cols) + divide: 3x b128 window, 4 outputs ----
    {
        const float* bp = &BPAD[i * 40 + j0];     // window cols j0-4 .. j0+7
        float4 w0 = *(const float4*)bp;
        float4 w1 = *(const float4*)(bp + 4);
        float4 w2 = *(const float4*)(bp + 8);
        float win[12] = {w0.x, w0.y, w0.z, w0.w, w1.x, w1.y, w1.z, w1.w,
                         w2.x, w2.y, w2.z, w2.w};
        float4 bl4 = *(const float4*)(ws_bleed + (tid << 2));
        float4 sm4;
        float s;
        s = 0.0f;
        #pragma unroll
        for (int t = 0; t < 9; ++t) s = __fmaf_rn(gk[t], win[0 + t], s);
        sm4.x = s / bl4.x;
        s = 0.0f;
        #pragma unroll
        for (int t = 0; t < 9; ++t) s = __fmaf_rn(gk[t], win[1 + t], s);
        sm4.y = s / bl4.y;
        s = 0.0f;
        #pragma unroll
        for (int t = 0; t < 9; ++t) s = __fmaf_rn(gk[t], win[2 + t], s);
        sm4.z = s / bl4.z;
        s = 0.0f;
        #pragma unroll
        for (int t = 0; t < 9; ++t) s = __fmaf_rn(gk[t], win[3 + t], s);
        sm4.w = s / bl4.w;
        *(float4*)&APAD[((i + 4) << 5) + j0] = sm4;
    }
    __syncthreads();

    // ---- fused sobel + mag: b128 row windows + uniform edge selects ----
    float jsr[4], isr[4], mr[4];
    {
        const float* S = APAD + 128;              // S[(r<<5)+c] == sm(r,c)
        const int im1 = i > 0 ? i - 1 : 0, ip1 = i < 31 ? i + 1 : 31;
        const bool le = (j0 == 0), re = (j0 == 28);
        // window cols j0-4 .. j0+7 ; used entries idx 3..8 with edge selects
        float am[6], a0[6], ap[6];
        {
            const float* r = S + (im1 << 5) + j0 - 4;
            float4 v0 = *(const float4*)r, v1 = *(const float4*)(r + 4), v2 = *(const float4*)(r + 8);
            am[0] = le ? v1.x : v0.w; am[1] = v1.x; am[2] = v1.y; am[3] = v1.z; am[4] = v1.w;
            am[5] = re ? v1.w : v2.x;
        }
        {
            const float* r = S + (i << 5) + j0 - 4;
            float4 v0 = *(const float4*)r, v1 = *(const float4*)(r + 4), v2 = *(const float4*)(r + 8);
            a0[0] = le ? v1.x : v0.w; a0[1] = v1.x; a0[2] = v1.y; a0[3] = v1.z; a0[4] = v1.w;
            a0[5] = re ? v1.w : v2.x;
        }
        {
            const float* r = S + (ip1 << 5) + j0 - 4;
            float4 v0 = *(const float4*)r, v1 = *(const float4*)(r + 4), v2 = *(const float4*)(r + 8);
            ap[0] = le ? v1.x : v0.w; ap[1] = v1.x; ap[2] = v1.y; ap[3] = v1.z; ap[4] = v1.w;
            ap[5] = re ? v1.w : v2.x;
        }
        #pragma unroll
        for (int q = 0; q < 4; ++q) {
            float tm = am[q + 2] - am[q];
            float t0 = a0[q + 2] - a0[q];
            float tp = ap[q + 2] - ap[q];
            float jsob = (tm + 2.0f * t0) + tp;
            float um = ap[q] - am[q];
            float u0 = ap[q + 1] - am[q + 1];
            float up = ap[q + 2] - am[q + 2];
            float isob = (um + 2.0f * u0) + up;
            jsr[q] = jsob; isr[q] = isob;
            float m = sqrtf((isob * isob + jsob * jsob) + 1e-9f);
            mr[q] = m;
            MPAD[(i + 1) * 34 + (j0 + q + 1)] = m;
        }
    }
    __syncthreads();

    // ---- branchless NMS; nibble masks + shfl_xor OR over the 8-lane row ----
    {
        unsigned int ew = er[i];
        unsigned int hn = 0u, ln = 0u;
        #pragma unroll
        for (int q = 0; q < 4; ++q) {
            int j = j0 + q;
            float iv = isr[q], jv = jsr[q], m = mr[q];
            float ai = fabsf(iv), aj = fabsf(jv);
            bool same = (iv >= 0.0f && jv >= 0.0f) || (iv <= 0.0f && jv <= 0.0f);
            bool opp  = (iv <= 0.0f && jv >= 0.0f) || (iv >= 0.0f && jv <= 0.0f);
            bool age  = (ai >= aj), ale = (ai <= aj);
            int oct = (opp && age) ? 3 : (opp && ale) ? 2 : (same && ale) ? 1 : 0;
            float ais = ai > 0.0f ? ai : 1.0f;
            float ajs = aj > 0.0f ? aj : 1.0f;
            float num = (oct == 3 || oct == 0) ? aj : ai;
            float den = (oct == 3) ? ais : (oct == 0) ? (ai + 1e-9f) : ajs;
            float wq = num / den;
            float omw = 1.0f - wq;
            int p2i = (oct >= 2) ? -1 : 1;
            int p1i = (oct == 0) ? 1 : (oct == 3) ? -1 : 0;
            int p1j = (oct == 1 || oct == 2) ? 1 : 0;
            int base = (i + 1) * 34 + (j + 1);
            float ipv = MPAD[base + p2i * 34 + 1] * wq + MPAD[base + p1i * 34 + p1j] * omw;
            float imv = MPAD[base - p2i * 34 - 1] * wq + MPAD[base - p1i * 34 - p1j] * omw;
            bool lm = (ipv <= m) && (imv <= m);
            bool eb = (ew >> j) & 1u;
            if (lm && eb && (m >= 0.2f)) hn |= (1u << j);
            if (lm && eb && (m >= 0.1f)) ln |= (1u << j);
        }
        #pragma unroll
        for (int mset = 1; mset < 8; mset <<= 1) {
            hn |= (unsigned int)__shfl_xor((int)hn, mset, 64);
            ln |= (unsigned int)__shfl_xor((int)ln, mset, 64);
        }
        if ((tid & 7) == 0) { hi32[i] = hn; lo32[i] = ln; }
    }
    __syncthreads();

    // ---- hysteresis: 8-connected flood of low seeded at high; wave 0 ----
    if (tid < 64) {
        unsigned int lw  = (tid < 32) ? lo32[tid] : 0u;
        unsigned int cur = (tid < 32) ? hi32[tid] : 0u;
        for (;;) {
            unsigned int sp  = cur | (cur << 1) | (cur >> 1);
            unsigned int upv = (unsigned int)__shfl((int)sp, (tid + 63) & 63, 64);
            if (tid == 0) upv = 0u;
            unsigned int dnv = (unsigned int)__shfl((int)sp, (tid + 1) & 63, 64);
            unsigned int nxt = (sp | upv | dnv) & lw;
            bool ch = (nxt != cur);
            cur = nxt;
            if (__ballot((int)ch) == 0ull) break;
        }
        if (tid < 32) fin32[tid] = cur;
    }
    __syncthreads();

    // ---- output: float4 per thread ----
    {
        unsigned int row = fin32[i];
        float4 o;
        o.x = ((row >> (j0    )) & 1u) ? 1.0f : -1.0f;
        o.y = ((row >> (j0 + 1)) & 1u) ? 1.0f : -1.0f;
        o.z = ((row >> (j0 + 2)) & 1u) ? 1.0f : -1.0f;
        o.w = ((row >> (j0 + 3)) & 1u) ? 1.0f : -1.0f;
        ((float4*)(out + (size_t)b * NPIX))[tid] = o;
    }
}

extern "C" void kernel_launch(void* const* d_in, const int* in_sizes, int n_in,
                              void* d_out, int out_size, void* d_ws, size_t ws_size,
                              hipStream_t stream) {
    const float* x    = (const float*)d_in[0];
    const float* mask = (const float*)d_in[1];
    float* out        = (float*)d_out;
    float* ws_bleed   = (float*)d_ws;
    unsigned int* ws_er = (unsigned int*)(ws_bleed + NPIX);
    float* ws_gk      = (float*)(ws_er + 32);
    int Bn = in_sizes[0] / (3 * NPIX);

    hipLaunchKernelGGL(canny_pre, dim3(1), dim3(256), 0, stream, x, mask, ws_bleed, ws_er, ws_gk);
    hipLaunchKernelGGL(canny_main, dim3(Bn), dim3(256), 0, stream, x, ws_bleed, ws_er, ws_gk, out);
}

// Round 9
// 48.681 us; speedup vs baseline: 1.2507x; 1.0827x over previous
//
#include <hip/hip_runtime.h>
#include <math.h>

#pragma clang fp contract(off)

#define NPIX 1024

// ---------------------------------------------------------------------------
// 9-tap gaussian (sigma=1, lw=4): phi in f64, normalized with numpy's pairwise
// sum order, cast to f32 — matches jnp.asarray(GAUSS_K, float32).
// ---------------------------------------------------------------------------
__device__ __forceinline__ void compute_gk(float gk[9]) {
    double phi[9];
    #pragma unroll
    for (int t = 0; t < 9; ++t) {
        double d = (double)(t - 4);
        phi[t] = exp(-0.5 * d * d);
    }
    double s = (((phi[0] + phi[1]) + (phi[2] + phi[3])) +
                ((phi[4] + phi[5]) + (phi[6] + phi[7]))) + phi[8];
    #pragma unroll
    for (int t = 0; t < 9; ++t) gk[t] = (float)(phi[t] / s);
}

// ---------------------------------------------------------------------------
// Kernel A (1 block, serial): gk -> ws_gk; bleed+1e-12 -> ws_bleed;
// er = erode3x3(mask!=0) & (mag2(batch0) > 0) -> ws_er.
// Vectorized 5-barrier structure (mirrors main kernel's phases).
// Thread (i = tid>>3, j0 = (tid&7)<<2) owns 4 consecutive pixels of row i.
// ---------------------------------------------------------------------------
__global__ __launch_bounds__(256) void canny_pre(const float* __restrict__ x,
                                                 const float* __restrict__ mask,
                                                 float* __restrict__ ws_bleed,
                                                 unsigned int* __restrict__ ws_er,
                                                 float* __restrict__ ws_gk) {
    __shared__ float APAD[40 * 32];    // (r+4)*32 + c ; rows 0-3,36-39 zero
    __shared__ float BPAD[32 * 40];    // r*40 + (c+4) ; cols 0-3,36-39 zero
    __shared__ float MPAD[34 * 34];    // (r+1)*34 + (c+1) ; ring zero (mask tile)
    __shared__ unsigned int er32[32];
    const int tid = threadIdx.x;
    const int i  = tid >> 3;
    const int j0 = (tid & 7) << 2;

    float gk[9];
    compute_gk(gk);
    if (tid < 9) ws_gk[tid] = gk[tid];

    // guards + mask tiles
    APAD[tid < 128 ? tid : 1024 + tid] = 0.0f;
    { int r = tid >> 3, c8 = tid & 7; BPAD[r * 40 + c8 + (c8 < 4 ? 0 : 32)] = 0.0f; }
    #pragma unroll
    for (int t = 0; t < 5; ++t) { int idx = tid + (t << 8); if (idx < 34 * 34) MPAD[idx] = 0.0f; }
    {
        float4 mk = ((const float4*)mask)[tid];
        *(float4*)&APAD[((i + 4) << 5) + j0] = mk;
        int mbase = (i + 1) * 34 + (j0 + 1);
        MPAD[mbase]     = mk.x;
        MPAD[mbase + 1] = mk.y;
        MPAD[mbase + 2] = mk.z;
        MPAD[mbase + 3] = mk.w;
    }
    __syncthreads();   // B1

    // mask blur H -> BPAD interior
    {
        float4 acc = make_float4(0.0f, 0.0f, 0.0f, 0.0f);
        #pragma unroll
        for (int t = 0; t < 9; ++t) {
            float4 v = *(const float4*)&APAD[((i + t) << 5) + j0];
            acc.x = __fmaf_rn(gk[t], v.x, acc.x);
            acc.y = __fmaf_rn(gk[t], v.y, acc.y);
            acc.z = __fmaf_rn(gk[t], v.z, acc.z);
            acc.w = __fmaf_rn(gk[t], v.w, acc.w);
        }
        *(float4*)&BPAD[i * 40 + j0 + 4] = acc;
    }
    asm volatile("" ::: "memory");

    // mask blur W (same-octet BPAD reads) -> bleed regs + global; erosion
    float bl4[4];
    {
        const float* bp = &BPAD[i * 40 + j0];
        float4 w0 = *(const float4*)bp;
        float4 w1 = *(const float4*)(bp + 4);
        float4 w2 = *(const float4*)(bp + 8);
        float win[12] = {w0.x, w0.y, w0.z, w0.w, w1.x, w1.y, w1.z, w1.w,
                         w2.x, w2.y, w2.z, w2.w};
        #pragma unroll
        for (int q = 0; q < 4; ++q) {
            float s = 0.0f;
            #pragma unroll
            for (int t = 0; t < 9; ++t) s = __fmaf_rn(gk[t], win[q + t], s);
            bl4[q] = s + 1e-12f;           // main divides by exactly this value
        }
        float4 wb = make_float4(bl4[0], bl4[1], bl4[2], bl4[3]);
        ((float4*)ws_bleed)[tid] = wb;
    }
    bool er2d[4];
    #pragma unroll
    for (int q = 0; q < 4; ++q) {
        int base = (i + 1) * 34 + (j0 + q + 1);
        bool e = true;
        #pragma unroll
        for (int di = -1; di <= 1; ++di)
            #pragma unroll
            for (int dj = -1; dj <= 1; ++dj)
                e = e && (MPAD[base + di * 34 + dj] != 0.0f);
        er2d[q] = e;
    }
    __syncthreads();   // B2

    // gray (image 0) -> APAD interior (overwrite; mask reads all done pre-B2)
    {
        const float4* xr = (const float4*)x;
        float4 r4 = xr[tid], g4 = xr[tid + 256], c4 = xr[tid + 512];
        float4 gy;
        gy.x = (r4.x * 0.5f + 0.5f) * 0.299f + (g4.x * 0.5f + 0.5f) * 0.587f + (c4.x * 0.5f + 0.5f) * 0.114f;
        gy.y = (r4.y * 0.5f + 0.5f) * 0.299f + (g4.y * 0.5f + 0.5f) * 0.587f + (c4.y * 0.5f + 0.5f) * 0.114f;
        gy.z = (r4.z * 0.5f + 0.5f) * 0.299f + (g4.z * 0.5f + 0.5f) * 0.587f + (c4.z * 0.5f + 0.5f) * 0.114f;
        gy.w = (r4.w * 0.5f + 0.5f) * 0.299f + (g4.w * 0.5f + 0.5f) * 0.587f + (c4.w * 0.5f + 0.5f) * 0.114f;
        *(float4*)&APAD[((i + 4) << 5) + j0] = gy;
    }
    __syncthreads();   // B3

    // gray blur H -> BPAD; (fence); blur W + div -> sm -> BPAD (same-octet)
    {
        float4 acc = make_float4(0.0f, 0.0f, 0.0f, 0.0f);
        #pragma unroll
        for (int t = 0; t < 9; ++t) {
            float4 v = *(const float4*)&APAD[((i + t) << 5) + j0];
            acc.x = __fmaf_rn(gk[t], v.x, acc.x);
            acc.y = __fmaf_rn(gk[t], v.y, acc.y);
            acc.z = __fmaf_rn(gk[t], v.z, acc.z);
            acc.w = __fmaf_rn(gk[t], v.w, acc.w);
        }
        *(float4*)&BPAD[i * 40 + j0 + 4] = acc;
    }
    asm volatile("" ::: "memory");
    {
        const float* bp = &BPAD[i * 40 + j0];
        float4 w0 = *(const float4*)bp;
        float4 w1 = *(const float4*)(bp + 4);
        float4 w2 = *(const float4*)(bp + 8);
        float win[12] = {w0.x, w0.y, w0.z, w0.w, w1.x, w1.y, w1.z, w1.w,
                         w2.x, w2.y, w2.z, w2.w};
        float4 sm4;
        float s;
        s = 0.0f;
        #pragma unroll
        for (int t = 0; t < 9; ++t) s = __fmaf_rn(gk[t], win[0 + t], s);
        sm4.x = s / bl4[0];
        s = 0.0f;
        #pragma unroll
        for (int t = 0; t < 9; ++t) s = __fmaf_rn(gk[t], win[1 + t], s);
        sm4.y = s / bl4[1];
        s = 0.0f;
        #pragma unroll
        for (int t = 0; t < 9; ++t) s = __fmaf_rn(gk[t], win[2 + t], s);
        sm4.z = s / bl4[2];
        s = 0.0f;
        #pragma unroll
        for (int t = 0; t < 9; ++t) s = __fmaf_rn(gk[t], win[3 + t], s);
        sm4.w = s / bl4[3];
        asm volatile("" ::: "memory");
        *(float4*)&BPAD[i * 40 + j0 + 4] = sm4;   // reads above precede (same wave)
    }
    __syncthreads();   // B4

    // sobel -> mag2; er bits; octet reduce; leaders -> er32
    {
        const int im1 = i > 0 ? i - 1 : 0, ip1 = i < 31 ? i + 1 : 31;
        const bool le = (j0 == 0), re = (j0 == 28);
        float am[6], a0[6], ap[6];
        {
            const float* r = BPAD + im1 * 40 + j0;
            float4 v0 = *(const float4*)r, v1 = *(const float4*)(r + 4), v2 = *(const float4*)(r + 8);
            am[0] = le ? v1.x : v0.w; am[1] = v1.x; am[2] = v1.y; am[3] = v1.z; am[4] = v1.w;
            am[5] = re ? v1.w : v2.x;
        }
        {
            const float* r = BPAD + i * 40 + j0;
            float4 v0 = *(const float4*)r, v1 = *(const float4*)(r + 4), v2 = *(const float4*)(r + 8);
            a0[0] = le ? v1.x : v0.w; a0[1] = v1.x; a0[2] = v1.y; a0[3] = v1.z; a0[4] = v1.w;
            a0[5] = re ? v1.w : v2.x;
        }
        {
            const float* r = BPAD + ip1 * 40 + j0;
            float4 v0 = *(const float4*)r, v1 = *(const float4*)(r + 4), v2 = *(const float4*)(r + 8);
            ap[0] = le ? v1.x : v0.w; ap[1] = v1.x; ap[2] = v1.y; ap[3] = v1.z; ap[4] = v1.w;
            ap[5] = re ? v1.w : v2.x;
        }
        unsigned int en = 0u;
        #pragma unroll
        for (int q = 0; q < 4; ++q) {
            float tm = am[q + 2] - am[q];
            float t0 = a0[q + 2] - a0[q];
            float tp = ap[q + 2] - ap[q];
            float jsob = (tm + 2.0f * t0) + tp;
            float um = ap[q] - am[q];
            float u0 = ap[q + 1] - am[q + 1];
            float up = ap[q + 2] - am[q + 2];
            float isob = (um + 2.0f * u0) + up;
            float m2 = isob * isob + jsob * jsob;   // isob^2 + jsob^2, ref order
            if (er2d[q] && (m2 > 0.0f)) en |= (1u << (j0 + q));
        }
        #pragma unroll
        for (int mset = 1; mset < 8; mset <<= 1)
            en |= (unsigned int)__shfl_xor((int)en, mset, 64);
        if ((tid & 7) == 0) er32[i] = en;
    }
    __syncthreads();   // B5
    if (tid < 32) ws_er[tid] = er32[tid];
}

// ---------------------------------------------------------------------------
// Kernel B: one block per image, 4 barriers.
// Phases: [init+gray] B1 [blurH->BPAD ; blurW same-octet ; sm->BPAD] B2
// [sobel ; mag->MPAD] B3 [NMS -> masks] B4 [flood on ALL waves ; output].
// blurH->blurW needs no barrier (row i's BPAD written/read by row i's own
// octet, same wave, DS in-order). Flood runs redundantly per wave.
// ---------------------------------------------------------------------------
__global__ __launch_bounds__(256) void canny_main(const float* __restrict__ x,
                                                  const float* __restrict__ ws_bleed,
                                                  const unsigned int* __restrict__ ws_er,
                                                  const float* __restrict__ ws_gk,
                                                  float* __restrict__ out) {
    __shared__ float APAD[40 * 32];    // (r+4)*32 + c ; rows 0-3,36-39 zero
    __shared__ float BPAD[32 * 40];    // r*40 + (c+4) ; cols 0-3,36-39 zero
    __shared__ float MPAD[34 * 34];    // (r+1)*34 + (c+1) ; ring zero
    __shared__ unsigned int er[32], hi32[32], lo32[32];
    const int tid = threadIdx.x;
    const int b = blockIdx.x;
    const int i  = tid >> 3;           // row 0..31
    const int j0 = (tid & 7) << 2;     // col base 0,4,...,28
    const int l  = tid & 63;

    float gk[9];
    #pragma unroll
    for (int t = 0; t < 9; ++t) gk[t] = ws_gk[t];

    // zero guards
    APAD[tid < 128 ? tid : 1024 + tid] = 0.0f;
    { int r = tid >> 3, c8 = tid & 7; BPAD[r * 40 + c8 + (c8 < 4 ? 0 : 32)] = 0.0f; }
    #pragma unroll
    for (int t = 0; t < 5; ++t) { int idx = tid + (t << 8); if (idx < 34 * 34) MPAD[idx] = 0.0f; }
    if (tid < 32) er[tid] = ws_er[tid];

    // gray: float4 channel loads -> APAD interior
    {
        const float4* xr = (const float4*)(x + (size_t)b * 3 * NPIX);
        float4 r4 = xr[tid], g4 = xr[tid + 256], c4 = xr[tid + 512];
        float4 gy;
        gy.x = (r4.x * 0.5f + 0.5f) * 0.299f + (g4.x * 0.5f + 0.5f) * 0.587f + (c4.x * 0.5f + 0.5f) * 0.114f;
        gy.y = (r4.y * 0.5f + 0.5f) * 0.299f + (g4.y * 0.5f + 0.5f) * 0.587f + (c4.y * 0.5f + 0.5f) * 0.114f;
        gy.z = (r4.z * 0.5f + 0.5f) * 0.299f + (g4.z * 0.5f + 0.5f) * 0.587f + (c4.z * 0.5f + 0.5f) * 0.114f;
        gy.w = (r4.w * 0.5f + 0.5f) * 0.299f + (g4.w * 0.5f + 0.5f) * 0.587f + (c4.w * 0.5f + 0.5f) * 0.114f;
        *(float4*)&APAD[((i + 4) << 5) + j0] = gy;
    }
    __syncthreads();   // B1

    // blur H (over rows): 9x b128, FMA chain ascending -> BPAD interior
    {
        float4 acc = make_float4(0.0f, 0.0f, 0.0f, 0.0f);
        #pragma unroll
        for (int t = 0; t < 9; ++t) {
            float4 v = *(const float4*)&APAD[((i + t) << 5) + j0];
            acc.x = __fmaf_rn(gk[t], v.x, acc.x);
            acc.y = __fmaf_rn(gk[t], v.y, acc.y);
            acc.z = __fmaf_rn(gk[t], v.z, acc.z);
            acc.w = __fmaf_rn(gk[t], v.w, acc.w);
        }
        *(float4*)&BPAD[i * 40 + j0 + 4] = acc;
    }
    asm volatile("" ::: "memory");

    // blur W + divide (same-octet BPAD reads; no barrier) -> sm -> BPAD
    {
        const float* bp = &BPAD[i * 40 + j0];     // window cols j0-4 .. j0+7
        float4 w0 = *(const float4*)bp;
        float4 w1 = *(const float4*)(bp + 4);
        float4 w2 = *(const float4*)(bp + 8);
        float win[12] = {w0.x, w0.y, w0.z, w0.w, w1.x, w1.y, w1.z, w1.w,
                         w2.x, w2.y, w2.z, w2.w};
        float4 bl4 = *(const float4*)(ws_bleed + (tid << 2));
        float4 sm4;
        float s;
        s = 0.0f;
        #pragma unroll
        for (int t = 0; t < 9; ++t) s = __fmaf_rn(gk[t], win[0 + t], s);
        sm4.x = s / bl4.x;
        s = 0.0f;
        #pragma unroll
        for (int t = 0; t < 9; ++t) s = __fmaf_rn(gk[t], win[1 + t], s);
        sm4.y = s / bl4.y;
        s = 0.0f;
        #pragma unroll
        for (int t = 0; t < 9; ++t) s = __fmaf_rn(gk[t], win[2 + t], s);
        sm4.z = s / bl4.z;
        s = 0.0f;
        #pragma unroll
        for (int t = 0; t < 9; ++t) s = __fmaf_rn(gk[t], win[3 + t], s);
        sm4.w = s / bl4.w;
        asm volatile("" ::: "memory");
        *(float4*)&BPAD[i * 40 + j0 + 4] = sm4;   // reads above precede (same wave)
    }
    __syncthreads();   // B2

    // fused sobel + mag: sm from BPAD (stride 40, col+4), mag -> MPAD + regs
    float jsr[4], isr[4], mr[4];
    {
        const int im1 = i > 0 ? i - 1 : 0, ip1 = i < 31 ? i + 1 : 31;
        const bool le = (j0 == 0), re = (j0 == 28);
        float am[6], a0[6], ap[6];
        {
            const float* r = BPAD + im1 * 40 + j0;
            float4 v0 = *(const float4*)r, v1 = *(const float4*)(r + 4), v2 = *(const float4*)(r + 8);
            am[0] = le ? v1.x : v0.w; am[1] = v1.x; am[2] = v1.y; am[3] = v1.z; am[4] = v1.w;
            am[5] = re ? v1.w : v2.x;
        }
        {
            const float* r = BPAD + i * 40 + j0;
            float4 v0 = *(const float4*)r, v1 = *(const float4*)(r + 4), v2 = *(const float4*)(r + 8);
            a0[0] = le ? v1.x : v0.w; a0[1] = v1.x; a0[2] = v1.y; a0[3] = v1.z; a0[4] = v1.w;
            a0[5] = re ? v1.w : v2.x;
        }
        {
            const float* r = BPAD + ip1 * 40 + j0;
            float4 v0 = *(const float4*)r, v1 = *(const float4*)(r + 4), v2 = *(const float4*)(r + 8);
            ap[0] = le ? v1.x : v0.w; ap[1] = v1.x; ap[2] = v1.y; ap[3] = v1.z; ap[4] = v1.w;
            ap[5] = re ? v1.w : v2.x;
        }
        #pragma unroll
        for (int q = 0; q < 4; ++q) {
            float tm = am[q + 2] - am[q];
            float t0 = a0[q + 2] - a0[q];
            float tp = ap[q + 2] - ap[q];
            float jsob = (tm + 2.0f * t0) + tp;
            float um = ap[q] - am[q];
            float u0 = ap[q + 1] - am[q + 1];
            float up = ap[q + 2] - am[q + 2];
            float isob = (um + 2.0f * u0) + up;
            jsr[q] = jsob; isr[q] = isob;
            float m = sqrtf((isob * isob + jsob * jsob) + 1e-9f);
            mr[q] = m;
            MPAD[(i + 1) * 34 + (j0 + q + 1)] = m;
        }
    }
    __syncthreads();   // B3

    // branchless NMS; nibble masks + shfl_xor OR over the 8-lane row octet
    {
        unsigned int ew = er[i];
        unsigned int hn = 0u, ln = 0u;
        #pragma unroll
        for (int q = 0; q < 4; ++q) {
            int j = j0 + q;
            float iv = isr[q], jv = jsr[q], m = mr[q];
            float ai = fabsf(iv), aj = fabsf(jv);
            bool same = (iv >= 0.0f && jv >= 0.0f) || (iv <= 0.0f && jv <= 0.0f);
            bool opp  = (iv <= 0.0f && jv >= 0.0f) || (iv >= 0.0f && jv <= 0.0f);
            bool age  = (ai >= aj), ale = (ai <= aj);
            int oct = (opp && age) ? 3 : (opp && ale) ? 2 : (same && ale) ? 1 : 0;
            float ais = ai > 0.0f ? ai : 1.0f;
            float ajs = aj > 0.0f ? aj : 1.0f;
            float num = (oct == 3 || oct == 0) ? aj : ai;
            float den = (oct == 3) ? ais : (oct == 0) ? (ai + 1e-9f) : ajs;
            float wq = num / den;
            float omw = 1.0f - wq;
            int p2i = (oct >= 2) ? -1 : 1;
            int p1i = (oct == 0) ? 1 : (oct == 3) ? -1 : 0;
            int p1j = (oct == 1 || oct == 2) ? 1 : 0;
            int base = (i + 1) * 34 + (j + 1);
            float ipv = MPAD[base + p2i * 34 + 1] * wq + MPAD[base + p1i * 34 + p1j] * omw;
            float imv = MPAD[base - p2i * 34 - 1] * wq + MPAD[base - p1i * 34 - p1j] * omw;
            bool lm = (ipv <= m) && (imv <= m);
            bool eb = (ew >> j) & 1u;
            if (lm && eb && (m >= 0.2f)) hn |= (1u << j);
            if (lm && eb && (m >= 0.1f)) ln |= (1u << j);
        }
        #pragma unroll
        for (int mset = 1; mset < 8; mset <<= 1) {
            hn |= (unsigned int)__shfl_xor((int)hn, mset, 64);
            ln |= (unsigned int)__shfl_xor((int)ln, mset, 64);
        }
        if ((tid & 7) == 0) { hi32[i] = hn; lo32[i] = ln; }
    }
    __syncthreads();   // B4

    // hysteresis flood on ALL waves (redundant, identical result per wave)
    unsigned int cur;
    {
        unsigned int lw = (l < 32) ? lo32[l] : 0u;
        cur             = (l < 32) ? hi32[l] : 0u;
        for (;;) {
            unsigned int sp  = cur | (cur << 1) | (cur >> 1);
            unsigned int upv = (unsigned int)__shfl((int)sp, (l + 63) & 63, 64);
            if (l == 0) upv = 0u;
            unsigned int dnv = (unsigned int)__shfl((int)sp, (l + 1) & 63, 64);
            unsigned int nxt = (sp | upv | dnv) & lw;
            bool ch = (nxt != cur);
            cur = nxt;
            if (__ballot((int)ch) == 0ull) break;
        }
    }

    // output: row word via shfl from lane i of own wave; float4 store
    {
        unsigned int wd = (unsigned int)__shfl((int)cur, i, 64);
        float4 o;
        o.x = ((wd >> (j0    )) & 1u) ? 1.0f : -1.0f;
        o.y = ((wd >> (j0 + 1)) & 1u) ? 1.0f : -1.0f;
        o.z = ((wd >> (j0 + 2)) & 1u) ? 1.0f : -1.0f;
        o.w = ((wd >> (j0 + 3)) & 1u) ? 1.0f : -1.0f;
        ((float4*)(out + (size_t)b * NPIX))[tid] = o;
    }
}

extern "C" void kernel_launch(void* const* d_in, const int* in_sizes, int n_in,
                              void* d_out, int out_size, void* d_ws, size_t ws_size,
                              hipStream_t stream) {
    const float* x    = (const float*)d_in[0];
    const float* mask = (const float*)d_in[1];
    float* out        = (float*)d_out;
    float* ws_bleed   = (float*)d_ws;
    unsigned int* ws_er = (unsigned int*)(ws_bleed + NPIX);
    float* ws_gk      = (float*)(ws_er + 32);
    int Bn = in_sizes[0] / (3 * NPIX);

    hipLaunchKernelGGL(canny_pre, dim3(1), dim3(256), 0, stream, x, mask, ws_bleed, ws_er, ws_gk);
    hipLaunchKernelGGL(canny_main, dim3(Bn), dim3(256), 0, stream, x, ws_bleed, ws_er, ws_gk, out);
}

// Round 10
// 48.478 us; speedup vs baseline: 1.2560x; 1.0042x over previous
//
#include <hip/hip_runtime.h>
#include <math.h>

#pragma clang fp contract(off)

#define NPIX 1024
#define MS 35   // MPAD row stride: 35 breaks the 4-way (2r+4o) bank aliasing of 34

// ---------------------------------------------------------------------------
// 9-tap gaussian (sigma=1, lw=4): phi in f64, normalized with numpy's pairwise
// sum order, cast to f32 — matches jnp.asarray(GAUSS_K, float32).
// ---------------------------------------------------------------------------
__device__ __forceinline__ void compute_gk(float gk[9]) {
    double phi[9];
    #pragma unroll
    for (int t = 0; t < 9; ++t) {
        double d = (double)(t - 4);
        phi[t] = exp(-0.5 * d * d);
    }
    double s = (((phi[0] + phi[1]) + (phi[2] + phi[3])) +
                ((phi[4] + phi[5]) + (phi[6] + phi[7]))) + phi[8];
    #pragma unroll
    for (int t = 0; t < 9; ++t) gk[t] = (float)(phi[t] / s);
}

// ---------------------------------------------------------------------------
// Kernel A (1 block, serial): gk -> ws_gk; bleed+1e-12 -> ws_bleed;
// er = erode3x3(mask!=0) & (mag2(batch0) > 0) -> ws_er.
// ---------------------------------------------------------------------------
__global__ __launch_bounds__(256) void canny_pre(const float* __restrict__ x,
                                                 const float* __restrict__ mask,
                                                 float* __restrict__ ws_bleed,
                                                 unsigned int* __restrict__ ws_er,
                                                 float* __restrict__ ws_gk) {
    __shared__ float APAD[40 * 32];    // (r+4)*32 + c ; rows 0-3,36-39 zero
    __shared__ float BPAD[32 * 40];    // r*40 + (c+4) ; cols 0-3,36-39 zero
    __shared__ float MPAD[34 * MS];    // (r+1)*MS + (c+1) ; ring zero (mask tile)
    __shared__ unsigned int er32[32];
    const int tid = threadIdx.x;
    const int i  = tid >> 3;
    const int j0 = (tid & 7) << 2;

    float gk[9];
    compute_gk(gk);
    if (tid < 9) ws_gk[tid] = gk[tid];

    // guards + mask tiles
    APAD[tid < 128 ? tid : 1024 + tid] = 0.0f;
    { int r = tid >> 3, c8 = tid & 7; BPAD[r * 40 + c8 + (c8 < 4 ? 0 : 32)] = 0.0f; }
    #pragma unroll
    for (int t = 0; t < 5; ++t) { int idx = tid + (t << 8); if (idx < 34 * MS) MPAD[idx] = 0.0f; }
    {
        float4 mk = ((const float4*)mask)[tid];
        *(float4*)&APAD[((i + 4) << 5) + j0] = mk;
        int mbase = (i + 1) * MS + (j0 + 1);
        MPAD[mbase]     = mk.x;
        MPAD[mbase + 1] = mk.y;
        MPAD[mbase + 2] = mk.z;
        MPAD[mbase + 3] = mk.w;
    }
    __syncthreads();   // B1

    // mask blur H -> BPAD interior
    {
        float4 acc = make_float4(0.0f, 0.0f, 0.0f, 0.0f);
        #pragma unroll
        for (int t = 0; t < 9; ++t) {
            float4 v = *(const float4*)&APAD[((i + t) << 5) + j0];
            acc.x = __fmaf_rn(gk[t], v.x, acc.x);
            acc.y = __fmaf_rn(gk[t], v.y, acc.y);
            acc.z = __fmaf_rn(gk[t], v.z, acc.z);
            acc.w = __fmaf_rn(gk[t], v.w, acc.w);
        }
        *(float4*)&BPAD[i * 40 + j0 + 4] = acc;
    }
    asm volatile("" ::: "memory");

    // mask blur W (same-octet BPAD reads) -> bleed regs + global; erosion
    float bl4[4];
    {
        const float* bp = &BPAD[i * 40 + j0];
        float4 w0 = *(const float4*)bp;
        float4 w1 = *(const float4*)(bp + 4);
        float4 w2 = *(const float4*)(bp + 8);
        float win[12] = {w0.x, w0.y, w0.z, w0.w, w1.x, w1.y, w1.z, w1.w,
                         w2.x, w2.y, w2.z, w2.w};
        #pragma unroll
        for (int q = 0; q < 4; ++q) {
            float s = 0.0f;
            #pragma unroll
            for (int t = 0; t < 9; ++t) s = __fmaf_rn(gk[t], win[q + t], s);
            bl4[q] = s + 1e-12f;           // main divides by exactly this value
        }
        float4 wb = make_float4(bl4[0], bl4[1], bl4[2], bl4[3]);
        ((float4*)ws_bleed)[tid] = wb;
    }
    bool er2d[4];
    #pragma unroll
    for (int q = 0; q < 4; ++q) {
        int base = (i + 1) * MS + (j0 + q + 1);
        bool e = true;
        #pragma unroll
        for (int di = -1; di <= 1; ++di)
            #pragma unroll
            for (int dj = -1; dj <= 1; ++dj)
                e = e && (MPAD[base + di * MS + dj] != 0.0f);
        er2d[q] = e;
    }
    __syncthreads();   // B2

    // gray (image 0) -> APAD interior
    {
        const float4* xr = (const float4*)x;
        float4 r4 = xr[tid], g4 = xr[tid + 256], c4 = xr[tid + 512];
        float4 gy;
        gy.x = (r4.x * 0.5f + 0.5f) * 0.299f + (g4.x * 0.5f + 0.5f) * 0.587f + (c4.x * 0.5f + 0.5f) * 0.114f;
        gy.y = (r4.y * 0.5f + 0.5f) * 0.299f + (g4.y * 0.5f + 0.5f) * 0.587f + (c4.y * 0.5f + 0.5f) * 0.114f;
        gy.z = (r4.z * 0.5f + 0.5f) * 0.299f + (g4.z * 0.5f + 0.5f) * 0.587f + (c4.z * 0.5f + 0.5f) * 0.114f;
        gy.w = (r4.w * 0.5f + 0.5f) * 0.299f + (g4.w * 0.5f + 0.5f) * 0.587f + (c4.w * 0.5f + 0.5f) * 0.114f;
        *(float4*)&APAD[((i + 4) << 5) + j0] = gy;
    }
    __syncthreads();   // B3

    // gray blur H -> BPAD; (fence); blur W + div -> sm -> BPAD (same-octet)
    {
        float4 acc = make_float4(0.0f, 0.0f, 0.0f, 0.0f);
        #pragma unroll
        for (int t = 0; t < 9; ++t) {
            float4 v = *(const float4*)&APAD[((i + t) << 5) + j0];
            acc.x = __fmaf_rn(gk[t], v.x, acc.x);
            acc.y = __fmaf_rn(gk[t], v.y, acc.y);
            acc.z = __fmaf_rn(gk[t], v.z, acc.z);
            acc.w = __fmaf_rn(gk[t], v.w, acc.w);
        }
        *(float4*)&BPAD[i * 40 + j0 + 4] = acc;
    }
    asm volatile("" ::: "memory");
    {
        const float* bp = &BPAD[i * 40 + j0];
        float4 w0 = *(const float4*)bp;
        float4 w1 = *(const float4*)(bp + 4);
        float4 w2 = *(const float4*)(bp + 8);
        float win[12] = {w0.x, w0.y, w0.z, w0.w, w1.x, w1.y, w1.z, w1.w,
                         w2.x, w2.y, w2.z, w2.w};
        float4 sm4;
        float s;
        s = 0.0f;
        #pragma unroll
        for (int t = 0; t < 9; ++t) s = __fmaf_rn(gk[t], win[0 + t], s);
        sm4.x = s / bl4[0];
        s = 0.0f;
        #pragma unroll
        for (int t = 0; t < 9; ++t) s = __fmaf_rn(gk[t], win[1 + t], s);
        sm4.y = s / bl4[1];
        s = 0.0f;
        #pragma unroll
        for (int t = 0; t < 9; ++t) s = __fmaf_rn(gk[t], win[2 + t], s);
        sm4.z = s / bl4[2];
        s = 0.0f;
        #pragma unroll
        for (int t = 0; t < 9; ++t) s = __fmaf_rn(gk[t], win[3 + t], s);
        sm4.w = s / bl4[3];
        asm volatile("" ::: "memory");
        *(float4*)&BPAD[i * 40 + j0 + 4] = sm4;   // reads above precede (same wave)
    }
    __syncthreads();   // B4

    // sobel -> mag2; er bits; octet reduce; leaders -> er32
    {
        const int im1 = i > 0 ? i - 1 : 0, ip1 = i < 31 ? i + 1 : 31;
        const bool le = (j0 == 0), re = (j0 == 28);
        float am[6], a0[6], ap[6];
        {
            const float* r = BPAD + im1 * 40 + j0;
            float4 v0 = *(const float4*)r, v1 = *(const float4*)(r + 4), v2 = *(const float4*)(r + 8);
            am[0] = le ? v1.x : v0.w; am[1] = v1.x; am[2] = v1.y; am[3] = v1.z; am[4] = v1.w;
            am[5] = re ? v1.w : v2.x;
        }
        {
            const float* r = BPAD + i * 40 + j0;
            float4 v0 = *(const float4*)r, v1 = *(const float4*)(r + 4), v2 = *(const float4*)(r + 8);
            a0[0] = le ? v1.x : v0.w; a0[1] = v1.x; a0[2] = v1.y; a0[3] = v1.z; a0[4] = v1.w;
            a0[5] = re ? v1.w : v2.x;
        }
        {
            const float* r = BPAD + ip1 * 40 + j0;
            float4 v0 = *(const float4*)r, v1 = *(const float4*)(r + 4), v2 = *(const float4*)(r + 8);
            ap[0] = le ? v1.x : v0.w; ap[1] = v1.x; ap[2] = v1.y; ap[3] = v1.z; ap[4] = v1.w;
            ap[5] = re ? v1.w : v2.x;
        }
        unsigned int en = 0u;
        #pragma unroll
        for (int q = 0; q < 4; ++q) {
            float tm = am[q + 2] - am[q];
            float t0 = a0[q + 2] - a0[q];
            float tp = ap[q + 2] - ap[q];
            float jsob = (tm + 2.0f * t0) + tp;
            float um = ap[q] - am[q];
            float u0 = ap[q + 1] - am[q + 1];
            float up = ap[q + 2] - am[q + 2];
            float isob = (um + 2.0f * u0) + up;
            float m2 = isob * isob + jsob * jsob;   // isob^2 + jsob^2, ref order
            if (er2d[q] && (m2 > 0.0f)) en |= (1u << (j0 + q));
        }
        #pragma unroll
        for (int mset = 1; mset < 8; mset <<= 1)
            en |= (unsigned int)__shfl_xor((int)en, mset, 64);
        if ((tid & 7) == 0) er32[i] = en;
    }
    __syncthreads();   // B5
    if (tid < 32) ws_er[tid] = er32[tid];
}

// ---------------------------------------------------------------------------
// Kernel B: one block per image, 4 barriers (round-9 structure), MPAD stride 35.
// ---------------------------------------------------------------------------
__global__ __launch_bounds__(256) void canny_main(const float* __restrict__ x,
                                                  const float* __restrict__ ws_bleed,
                                                  const unsigned int* __restrict__ ws_er,
                                                  const float* __restrict__ ws_gk,
                                                  float* __restrict__ out) {
    __shared__ float APAD[40 * 32];    // (r+4)*32 + c ; rows 0-3,36-39 zero
    __shared__ float BPAD[32 * 40];    // r*40 + (c+4) ; cols 0-3,36-39 zero
    __shared__ float MPAD[34 * MS];    // (r+1)*MS + (c+1) ; ring zero
    __shared__ unsigned int er[32], hi32[32], lo32[32];
    const int tid = threadIdx.x;
    const int b = blockIdx.x;
    const int i  = tid >> 3;           // row 0..31
    const int j0 = (tid & 7) << 2;     // col base 0,4,...,28
    const int l  = tid & 63;

    float gk[9];
    #pragma unroll
    for (int t = 0; t < 9; ++t) gk[t] = ws_gk[t];

    // zero guards
    APAD[tid < 128 ? tid : 1024 + tid] = 0.0f;
    { int r = tid >> 3, c8 = tid & 7; BPAD[r * 40 + c8 + (c8 < 4 ? 0 : 32)] = 0.0f; }
    #pragma unroll
    for (int t = 0; t < 5; ++t) { int idx = tid + (t << 8); if (idx < 34 * MS) MPAD[idx] = 0.0f; }
    if (tid < 32) er[tid] = ws_er[tid];

    // gray: float4 channel loads -> APAD interior
    {
        const float4* xr = (const float4*)(x + (size_t)b * 3 * NPIX);
        float4 r4 = xr[tid], g4 = xr[tid + 256], c4 = xr[tid + 512];
        float4 gy;
        gy.x = (r4.x * 0.5f + 0.5f) * 0.299f + (g4.x * 0.5f + 0.5f) * 0.587f + (c4.x * 0.5f + 0.5f) * 0.114f;
        gy.y = (r4.y * 0.5f + 0.5f) * 0.299f + (g4.y * 0.5f + 0.5f) * 0.587f + (c4.y * 0.5f + 0.5f) * 0.114f;
        gy.z = (r4.z * 0.5f + 0.5f) * 0.299f + (g4.z * 0.5f + 0.5f) * 0.587f + (c4.z * 0.5f + 0.5f) * 0.114f;
        gy.w = (r4.w * 0.5f + 0.5f) * 0.299f + (g4.w * 0.5f + 0.5f) * 0.587f + (c4.w * 0.5f + 0.5f) * 0.114f;
        *(float4*)&APAD[((i + 4) << 5) + j0] = gy;
    }
    __syncthreads();   // B1

    // blur H (over rows): 9x b128, FMA chain ascending -> BPAD interior
    {
        float4 acc = make_float4(0.0f, 0.0f, 0.0f, 0.0f);
        #pragma unroll
        for (int t = 0; t < 9; ++t) {
            float4 v = *(const float4*)&APAD[((i + t) << 5) + j0];
            acc.x = __fmaf_rn(gk[t], v.x, acc.x);
            acc.y = __fmaf_rn(gk[t], v.y, acc.y);
            acc.z = __fmaf_rn(gk[t], v.z, acc.z);
            acc.w = __fmaf_rn(gk[t], v.w, acc.w);
        }
        *(float4*)&BPAD[i * 40 + j0 + 4] = acc;
    }
    asm volatile("" ::: "memory");

    // blur W + divide (same-octet BPAD reads; no barrier) -> sm -> BPAD
    {
        const float* bp = &BPAD[i * 40 + j0];     // window cols j0-4 .. j0+7
        float4 w0 = *(const float4*)bp;
        float4 w1 = *(const float4*)(bp + 4);
        float4 w2 = *(const float4*)(bp + 8);
        float win[12] = {w0.x, w0.y, w0.z, w0.w, w1.x, w1.y, w1.z, w1.w,
                         w2.x, w2.y, w2.z, w2.w};
        float4 bl4 = *(const float4*)(ws_bleed + (tid << 2));
        float4 sm4;
        float s;
        s = 0.0f;
        #pragma unroll
        for (int t = 0; t < 9; ++t) s = __fmaf_rn(gk[t], win[0 + t], s);
        sm4.x = s / bl4.x;
        s = 0.0f;
        #pragma unroll
        for (int t = 0; t < 9; ++t) s = __fmaf_rn(gk[t], win[1 + t], s);
        sm4.y = s / bl4.y;
        s = 0.0f;
        #pragma unroll
        for (int t = 0; t < 9; ++t) s = __fmaf_rn(gk[t], win[2 + t], s);
        sm4.z = s / bl4.z;
        s = 0.0f;
        #pragma unroll
        for (int t = 0; t < 9; ++t) s = __fmaf_rn(gk[t], win[3 + t], s);
        sm4.w = s / bl4.w;
        asm volatile("" ::: "memory");
        *(float4*)&BPAD[i * 40 + j0 + 4] = sm4;   // reads above precede (same wave)
    }
    __syncthreads();   // B2

    // fused sobel + mag: sm from BPAD (stride 40, col+4), mag -> MPAD + regs
    float jsr[4], isr[4], mr[4];
    {
        const int im1 = i > 0 ? i - 1 : 0, ip1 = i < 31 ? i + 1 : 31;
        const bool le = (j0 == 0), re = (j0 == 28);
        float am[6], a0[6], ap[6];
        {
            const float* r = BPAD + im1 * 40 + j0;
            float4 v0 = *(const float4*)r, v1 = *(const float4*)(r + 4), v2 = *(const float4*)(r + 8);
            am[0] = le ? v1.x : v0.w; am[1] = v1.x; am[2] = v1.y; am[3] = v1.z; am[4] = v1.w;
            am[5] = re ? v1.w : v2.x;
        }
        {
            const float* r = BPAD + i * 40 + j0;
            float4 v0 = *(const float4*)r, v1 = *(const float4*)(r + 4), v2 = *(const float4*)(r + 8);
            a0[0] = le ? v1.x : v0.w; a0[1] = v1.x; a0[2] = v1.y; a0[3] = v1.z; a0[4] = v1.w;
            a0[5] = re ? v1.w : v2.x;
        }
        {
            const float* r = BPAD + ip1 * 40 + j0;
            float4 v0 = *(const float4*)r, v1 = *(const float4*)(r + 4), v2 = *(const float4*)(r + 8);
            ap[0] = le ? v1.x : v0.w; ap[1] = v1.x; ap[2] = v1.y; ap[3] = v1.z; ap[4] = v1.w;
            ap[5] = re ? v1.w : v2.x;
        }
        #pragma unroll
        for (int q = 0; q < 4; ++q) {
            float tm = am[q + 2] - am[q];
            float t0 = a0[q + 2] - a0[q];
            float tp = ap[q + 2] - ap[q];
            float jsob = (tm + 2.0f * t0) + tp;
            float um = ap[q] - am[q];
            float u0 = ap[q + 1] - am[q + 1];
            float up = ap[q + 2] - am[q + 2];
            float isob = (um + 2.0f * u0) + up;
            jsr[q] = jsob; isr[q] = isob;
            float m = sqrtf((isob * isob + jsob * jsob) + 1e-9f);
            mr[q] = m;
            MPAD[(i + 1) * MS + (j0 + q + 1)] = m;
        }
    }
    __syncthreads();   // B3

    // branchless NMS; nibble masks + shfl_xor OR over the 8-lane row octet
    {
        unsigned int ew = er[i];
        unsigned int hn = 0u, ln = 0u;
        #pragma unroll
        for (int q = 0; q < 4; ++q) {
            int j = j0 + q;
            float iv = isr[q], jv = jsr[q], m = mr[q];
            float ai = fabsf(iv), aj = fabsf(jv);
            bool same = (iv >= 0.0f && jv >= 0.0f) || (iv <= 0.0f && jv <= 0.0f);
            bool opp  = (iv <= 0.0f && jv >= 0.0f) || (iv >= 0.0f && jv <= 0.0f);
            bool age  = (ai >= aj), ale = (ai <= aj);
            int oct = (opp && age) ? 3 : (opp && ale) ? 2 : (same && ale) ? 1 : 0;
            float ais = ai > 0.0f ? ai : 1.0f;
            float ajs = aj > 0.0f ? aj : 1.0f;
            float num = (oct == 3 || oct == 0) ? aj : ai;
            float den = (oct == 3) ? ais : (oct == 0) ? (ai + 1e-9f) : ajs;
            float wq = num / den;
            float omw = 1.0f - wq;
            int p2i = (oct >= 2) ? -1 : 1;
            int p1i = (oct == 0) ? 1 : (oct == 3) ? -1 : 0;
            int p1j = (oct == 1 || oct == 2) ? 1 : 0;
            int base = (i + 1) * MS + (j + 1);
            float ipv = MPAD[base + p2i * MS + 1] * wq + MPAD[base + p1i * MS + p1j] * omw;
            float imv = MPAD[base - p2i * MS - 1] * wq + MPAD[base - p1i * MS - p1j] * omw;
            bool lm = (ipv <= m) && (imv <= m);
            bool eb = (ew >> j) & 1u;
            if (lm && eb && (m >= 0.2f)) hn |= (1u << j);
            if (lm && eb && (m >= 0.1f)) ln |= (1u << j);
        }
        #pragma unroll
        for (int mset = 1; mset < 8; mset <<= 1) {
            hn |= (unsigned int)__shfl_xor((int)hn, mset, 64);
            ln |= (unsigned int)__shfl_xor((int)ln, mset, 64);
        }
        if ((tid & 7) == 0) { hi32[i] = hn; lo32[i] = ln; }
    }
    __syncthreads();   // B4

    // hysteresis flood on ALL waves (redundant, identical result per wave)
    unsigned int cur;
    {
        unsigned int lw = (l < 32) ? lo32[l] : 0u;
        cur             = (l < 32) ? hi32[l] : 0u;
        for (;;) {
            unsigned int sp  = cur | (cur << 1) | (cur >> 1);
            unsigned int upv = (unsigned int)__shfl((int)sp, (l + 63) & 63, 64);
            if (l == 0) upv = 0u;
            unsigned int dnv = (unsigned int)__shfl((int)sp, (l + 1) & 63, 64);
            unsigned int nxt = (sp | upv | dnv) & lw;
            bool ch = (nxt != cur);
            cur = nxt;
            if (__ballot((int)ch) == 0ull) break;
        }
    }

    // output: row word via shfl from lane i of own wave; float4 store
    {
        unsigned int wd = (unsigned int)__shfl((int)cur, i, 64);
        float4 o;
        o.x = ((wd >> (j0    )) & 1u) ? 1.0f : -1.0f;
        o.y = ((wd >> (j0 + 1)) & 1u) ? 1.0f : -1.0f;
        o.z = ((wd >> (j0 + 2)) & 1u) ? 1.0f : -1.0f;
        o.w = ((wd >> (j0 + 3)) & 1u) ? 1.0f : -1.0f;
        ((float4*)(out + (size_t)b * NPIX))[tid] = o;
    }
}

extern "C" void kernel_launch(void* const* d_in, const int* in_sizes, int n_in,
                              void* d_out, int out_size, void* d_ws, size_t ws_size,
                              hipStream_t stream) {
    const float* x    = (const float*)d_in[0];
    const float* mask = (const float*)d_in[1];
    float* out        = (float*)d_out;
    float* ws_bleed   = (float*)d_ws;
    unsigned int* ws_er = (unsigned int*)(ws_bleed + NPIX);
    float* ws_gk      = (float*)(ws_er + 32);
    int Bn = in_sizes[0] / (3 * NPIX);

    hipLaunchKernelGGL(canny_pre, dim3(1), dim3(256), 0, stream, x, mask, ws_bleed, ws_er, ws_gk);
    hipLaunchKernelGGL(canny_main, dim3(Bn), dim3(256), 0, stream, x, ws_bleed, ws_er, ws_gk, out);
}

// Round 11
// 46.784 us; speedup vs baseline: 1.3015x; 1.0362x over previous
//
#include <hip/hip_runtime.h>
#include <math.h>

#pragma clang fp contract(off)

#define NPIX 1024
#define MS 35   // MPAD row stride (35 keeps worst aliasing at 2-way)

// ---------------------------------------------------------------------------
// 9-tap gaussian (sigma=1, lw=4): phi in f64, normalized with numpy's pairwise
// sum order, cast to f32 — matches jnp.asarray(GAUSS_K, float32).
// ---------------------------------------------------------------------------
__device__ __forceinline__ void compute_gk(float gk[9]) {
    double phi[9];
    #pragma unroll
    for (int t = 0; t < 9; ++t) {
        double d = (double)(t - 4);
        phi[t] = exp(-0.5 * d * d);
    }
    double s = (((phi[0] + phi[1]) + (phi[2] + phi[3])) +
                ((phi[4] + phi[5]) + (phi[6] + phi[7]))) + phi[8];
    #pragma unroll
    for (int t = 0; t < 9; ++t) gk[t] = (float)(phi[t] / s);
}

// ---------------------------------------------------------------------------
// Kernel A (1 block, serial): gk -> ws_gk; 1/(double)(bleed+1e-12) -> ws_blrcp;
// er = erode3x3(mask!=0) & (mag2(batch0) > 0) -> ws_er.
// (Correctly-rounded f32 division s/bl == fl32(fl64(s)*fl64(1/bl)) by the
//  exclusion-zone lemma — quotient of two 24-bit floats is never a midpoint.)
// ---------------------------------------------------------------------------
__global__ __launch_bounds__(256) void canny_pre(const float* __restrict__ x,
                                                 const float* __restrict__ mask,
                                                 double* __restrict__ ws_blrcp,
                                                 unsigned int* __restrict__ ws_er,
                                                 float* __restrict__ ws_gk) {
    __shared__ float APAD[40 * 32];    // (r+4)*32 + c ; rows 0-3,36-39 zero
    __shared__ float BPAD[32 * 40];    // r*40 + (c+4) ; cols 0-3,36-39 zero
    __shared__ float MPAD[34 * MS];    // (r+1)*MS + (c+1) ; ring zero (mask tile)
    __shared__ unsigned int er32[32];
    const int tid = threadIdx.x;
    const int i  = tid >> 3;
    const int j0 = (tid & 7) << 2;

    float gk[9];
    compute_gk(gk);
    if (tid < 9) ws_gk[tid] = gk[tid];

    // guards + mask tiles
    APAD[tid < 128 ? tid : 1024 + tid] = 0.0f;
    { int r = tid >> 3, c8 = tid & 7; BPAD[r * 40 + c8 + (c8 < 4 ? 0 : 32)] = 0.0f; }
    #pragma unroll
    for (int t = 0; t < 5; ++t) { int idx = tid + (t << 8); if (idx < 34 * MS) MPAD[idx] = 0.0f; }
    {
        float4 mk = ((const float4*)mask)[tid];
        *(float4*)&APAD[((i + 4) << 5) + j0] = mk;
        int mbase = (i + 1) * MS + (j0 + 1);
        MPAD[mbase]     = mk.x;
        MPAD[mbase + 1] = mk.y;
        MPAD[mbase + 2] = mk.z;
        MPAD[mbase + 3] = mk.w;
    }
    __syncthreads();   // B1

    // mask blur H -> BPAD interior
    {
        float4 acc = make_float4(0.0f, 0.0f, 0.0f, 0.0f);
        #pragma unroll
        for (int t = 0; t < 9; ++t) {
            float4 v = *(const float4*)&APAD[((i + t) << 5) + j0];
            acc.x = __fmaf_rn(gk[t], v.x, acc.x);
            acc.y = __fmaf_rn(gk[t], v.y, acc.y);
            acc.z = __fmaf_rn(gk[t], v.z, acc.z);
            acc.w = __fmaf_rn(gk[t], v.w, acc.w);
        }
        *(float4*)&BPAD[i * 40 + j0 + 4] = acc;
    }
    asm volatile("" ::: "memory");

    // mask blur W (same-octet BPAD reads) -> bleed regs; rcp -> global; erosion
    float bl4[4];
    {
        const float* bp = &BPAD[i * 40 + j0];
        float4 w0 = *(const float4*)bp;
        float4 w1 = *(const float4*)(bp + 4);
        float4 w2 = *(const float4*)(bp + 8);
        float win[12] = {w0.x, w0.y, w0.z, w0.w, w1.x, w1.y, w1.z, w1.w,
                         w2.x, w2.y, w2.z, w2.w};
        #pragma unroll
        for (int q = 0; q < 4; ++q) {
            float s = 0.0f;
            #pragma unroll
            for (int t = 0; t < 9; ++t) s = __fmaf_rn(gk[t], win[q + t], s);
            bl4[q] = s + 1e-12f;           // the exact f32 divisor
            ws_blrcp[(i << 5) + j0 + q] = 1.0 / (double)bl4[q];
        }
    }
    bool er2d[4];
    #pragma unroll
    for (int q = 0; q < 4; ++q) {
        int base = (i + 1) * MS + (j0 + q + 1);
        bool e = true;
        #pragma unroll
        for (int di = -1; di <= 1; ++di)
            #pragma unroll
            for (int dj = -1; dj <= 1; ++dj)
                e = e && (MPAD[base + di * MS + dj] != 0.0f);
        er2d[q] = e;
    }
    __syncthreads();   // B2

    // gray (image 0) -> APAD interior
    {
        const float4* xr = (const float4*)x;
        float4 r4 = xr[tid], g4 = xr[tid + 256], c4 = xr[tid + 512];
        float4 gy;
        gy.x = (r4.x * 0.5f + 0.5f) * 0.299f + (g4.x * 0.5f + 0.5f) * 0.587f + (c4.x * 0.5f + 0.5f) * 0.114f;
        gy.y = (r4.y * 0.5f + 0.5f) * 0.299f + (g4.y * 0.5f + 0.5f) * 0.587f + (c4.y * 0.5f + 0.5f) * 0.114f;
        gy.z = (r4.z * 0.5f + 0.5f) * 0.299f + (g4.z * 0.5f + 0.5f) * 0.587f + (c4.z * 0.5f + 0.5f) * 0.114f;
        gy.w = (r4.w * 0.5f + 0.5f) * 0.299f + (g4.w * 0.5f + 0.5f) * 0.587f + (c4.w * 0.5f + 0.5f) * 0.114f;
        *(float4*)&APAD[((i + 4) << 5) + j0] = gy;
    }
    __syncthreads();   // B3

    // gray blur H -> BPAD; (fence); blur W + f32 div -> sm -> BPAD (same-octet)
    {
        float4 acc = make_float4(0.0f, 0.0f, 0.0f, 0.0f);
        #pragma unroll
        for (int t = 0; t < 9; ++t) {
            float4 v = *(const float4*)&APAD[((i + t) << 5) + j0];
            acc.x = __fmaf_rn(gk[t], v.x, acc.x);
            acc.y = __fmaf_rn(gk[t], v.y, acc.y);
            acc.z = __fmaf_rn(gk[t], v.z, acc.z);
            acc.w = __fmaf_rn(gk[t], v.w, acc.w);
        }
        *(float4*)&BPAD[i * 40 + j0 + 4] = acc;
    }
    asm volatile("" ::: "memory");
    {
        const float* bp = &BPAD[i * 40 + j0];
        float4 w0 = *(const float4*)bp;
        float4 w1 = *(const float4*)(bp + 4);
        float4 w2 = *(const float4*)(bp + 8);
        float win[12] = {w0.x, w0.y, w0.z, w0.w, w1.x, w1.y, w1.z, w1.w,
                         w2.x, w2.y, w2.z, w2.w};
        float4 sm4;
        float s;
        s = 0.0f;
        #pragma unroll
        for (int t = 0; t < 9; ++t) s = __fmaf_rn(gk[t], win[0 + t], s);
        sm4.x = s / bl4[0];
        s = 0.0f;
        #pragma unroll
        for (int t = 0; t < 9; ++t) s = __fmaf_rn(gk[t], win[1 + t], s);
        sm4.y = s / bl4[1];
        s = 0.0f;
        #pragma unroll
        for (int t = 0; t < 9; ++t) s = __fmaf_rn(gk[t], win[2 + t], s);
        sm4.z = s / bl4[2];
        s = 0.0f;
        #pragma unroll
        for (int t = 0; t < 9; ++t) s = __fmaf_rn(gk[t], win[3 + t], s);
        sm4.w = s / bl4[3];
        asm volatile("" ::: "memory");
        *(float4*)&BPAD[i * 40 + j0 + 4] = sm4;   // reads above precede (same wave)
    }
    __syncthreads();   // B4

    // sobel -> mag2; er bits; octet reduce; leaders -> er32
    {
        const int im1 = i > 0 ? i - 1 : 0, ip1 = i < 31 ? i + 1 : 31;
        const bool le = (j0 == 0), re = (j0 == 28);
        float am[6], a0[6], ap[6];
        {
            const float* r = BPAD + im1 * 40 + j0;
            float4 v0 = *(const float4*)r, v1 = *(const float4*)(r + 4), v2 = *(const float4*)(r + 8);
            am[0] = le ? v1.x : v0.w; am[1] = v1.x; am[2] = v1.y; am[3] = v1.z; am[4] = v1.w;
            am[5] = re ? v1.w : v2.x;
        }
        {
            const float* r = BPAD + i * 40 + j0;
            float4 v0 = *(const float4*)r, v1 = *(const float4*)(r + 4), v2 = *(const float4*)(r + 8);
            a0[0] = le ? v1.x : v0.w; a0[1] = v1.x; a0[2] = v1.y; a0[3] = v1.z; a0[4] = v1.w;
            a0[5] = re ? v1.w : v2.x;
        }
        {
            const float* r = BPAD + ip1 * 40 + j0;
            float4 v0 = *(const float4*)r, v1 = *(const float4*)(r + 4), v2 = *(const float4*)(r + 8);
            ap[0] = le ? v1.x : v0.w; ap[1] = v1.x; ap[2] = v1.y; ap[3] = v1.z; ap[4] = v1.w;
            ap[5] = re ? v1.w : v2.x;
        }
        unsigned int en = 0u;
        #pragma unroll
        for (int q = 0; q < 4; ++q) {
            float tm = am[q + 2] - am[q];
            float t0 = a0[q + 2] - a0[q];
            float tp = ap[q + 2] - ap[q];
            float jsob = (tm + 2.0f * t0) + tp;
            float um = ap[q] - am[q];
            float u0 = ap[q + 1] - am[q + 1];
            float up = ap[q + 2] - am[q + 2];
            float isob = (um + 2.0f * u0) + up;
            float m2 = isob * isob + jsob * jsob;   // isob^2 + jsob^2, ref order
            if (er2d[q] && (m2 > 0.0f)) en |= (1u << (j0 + q));
        }
        #pragma unroll
        for (int mset = 1; mset < 8; mset <<= 1)
            en |= (unsigned int)__shfl_xor((int)en, mset, 64);
        if ((tid & 7) == 0) er32[i] = en;
    }
    __syncthreads();   // B5
    if (tid < 32) ws_er[tid] = er32[tid];
}

// ---------------------------------------------------------------------------
// Kernel B: one block per image, 4 barriers (round-10 structure).
// Bleed division via precomputed f64 reciprocal (bit-exact, see pre-kernel).
// MPAD: only the 132-cell guard ring is zeroed.
// ---------------------------------------------------------------------------
__global__ __launch_bounds__(256) void canny_main(const float* __restrict__ x,
                                                  const double* __restrict__ ws_blrcp,
                                                  const unsigned int* __restrict__ ws_er,
                                                  const float* __restrict__ ws_gk,
                                                  float* __restrict__ out) {
    __shared__ float APAD[40 * 32];    // (r+4)*32 + c ; rows 0-3,36-39 zero
    __shared__ float BPAD[32 * 40];    // r*40 + (c+4) ; cols 0-3,36-39 zero
    __shared__ float MPAD[34 * MS];    // (r+1)*MS + (c+1) ; ring zero
    __shared__ unsigned int er[32], hi32[32], lo32[32];
    const int tid = threadIdx.x;
    const int b = blockIdx.x;
    const int i  = tid >> 3;           // row 0..31
    const int j0 = (tid & 7) << 2;     // col base 0,4,...,28
    const int l  = tid & 63;

    float gk[9];
    #pragma unroll
    for (int t = 0; t < 9; ++t) gk[t] = ws_gk[t];

    // hoisted bleed reciprocals (needed in blurW)
    double rc[4];
    #pragma unroll
    for (int q = 0; q < 4; ++q) rc[q] = ws_blrcp[(i << 5) + j0 + q];

    // zero guards (MPAD: ring cells only)
    APAD[tid < 128 ? tid : 1024 + tid] = 0.0f;
    { int r = tid >> 3, c8 = tid & 7; BPAD[r * 40 + c8 + (c8 < 4 ? 0 : 32)] = 0.0f; }
    if (tid < 132) {
        int idx;
        if (tid < 34)       idx = tid;                    // row 0, cols 0..33
        else if (tid < 68)  idx = 33 * MS + (tid - 34);   // row 33
        else if (tid < 100) idx = (tid - 67) * MS;        // col 0, rows 1..32
        else                idx = (tid - 99) * MS + 33;   // col 33, rows 1..32
        MPAD[idx] = 0.0f;
    }
    if (tid < 32) er[tid] = ws_er[tid];

    // gray: float4 channel loads -> APAD interior
    {
        const float4* xr = (const float4*)(x + (size_t)b * 3 * NPIX);
        float4 r4 = xr[tid], g4 = xr[tid + 256], c4 = xr[tid + 512];
        float4 gy;
        gy.x = (r4.x * 0.5f + 0.5f) * 0.299f + (g4.x * 0.5f + 0.5f) * 0.587f + (c4.x * 0.5f + 0.5f) * 0.114f;
        gy.y = (r4.y * 0.5f + 0.5f) * 0.299f + (g4.y * 0.5f + 0.5f) * 0.587f + (c4.y * 0.5f + 0.5f) * 0.114f;
        gy.z = (r4.z * 0.5f + 0.5f) * 0.299f + (g4.z * 0.5f + 0.5f) * 0.587f + (c4.z * 0.5f + 0.5f) * 0.114f;
        gy.w = (r4.w * 0.5f + 0.5f) * 0.299f + (g4.w * 0.5f + 0.5f) * 0.587f + (c4.w * 0.5f + 0.5f) * 0.114f;
        *(float4*)&APAD[((i + 4) << 5) + j0] = gy;
    }
    __syncthreads();   // B1

    // blur H (over rows): 9x b128, FMA chain ascending -> BPAD interior
    {
        float4 acc = make_float4(0.0f, 0.0f, 0.0f, 0.0f);
        #pragma unroll
        for (int t = 0; t < 9; ++t) {
            float4 v = *(const float4*)&APAD[((i + t) << 5) + j0];
            acc.x = __fmaf_rn(gk[t], v.x, acc.x);
            acc.y = __fmaf_rn(gk[t], v.y, acc.y);
            acc.z = __fmaf_rn(gk[t], v.z, acc.z);
            acc.w = __fmaf_rn(gk[t], v.w, acc.w);
        }
        *(float4*)&BPAD[i * 40 + j0 + 4] = acc;
    }
    asm volatile("" ::: "memory");

    // blur W + divide-by-constant via f64 reciprocal (bit-exact) -> sm -> BPAD
    {
        const float* bp = &BPAD[i * 40 + j0];     // window cols j0-4 .. j0+7
        float4 w0 = *(const float4*)bp;
        float4 w1 = *(const float4*)(bp + 4);
        float4 w2 = *(const float4*)(bp + 8);
        float win[12] = {w0.x, w0.y, w0.z, w0.w, w1.x, w1.y, w1.z, w1.w,
                         w2.x, w2.y, w2.z, w2.w};
        float4 sm4;
        float s;
        s = 0.0f;
        #pragma unroll
        for (int t = 0; t < 9; ++t) s = __fmaf_rn(gk[t], win[0 + t], s);
        sm4.x = (float)((double)s * rc[0]);
        s = 0.0f;
        #pragma unroll
        for (int t = 0; t < 9; ++t) s = __fmaf_rn(gk[t], win[1 + t], s);
        sm4.y = (float)((double)s * rc[1]);
        s = 0.0f;
        #pragma unroll
        for (int t = 0; t < 9; ++t) s = __fmaf_rn(gk[t], win[2 + t], s);
        sm4.z = (float)((double)s * rc[2]);
        s = 0.0f;
        #pragma unroll
        for (int t = 0; t < 9; ++t) s = __fmaf_rn(gk[t], win[3 + t], s);
        sm4.w = (float)((double)s * rc[3]);
        asm volatile("" ::: "memory");
        *(float4*)&BPAD[i * 40 + j0 + 4] = sm4;   // reads above precede (same wave)
    }
    __syncthreads();   // B2

    // fused sobel + mag: sm from BPAD (stride 40, col+4), mag -> MPAD + regs
    float jsr[4], isr[4], mr[4];
    {
        const int im1 = i > 0 ? i - 1 : 0, ip1 = i < 31 ? i + 1 : 31;
        const bool le = (j0 == 0), re = (j0 == 28);
        float am[6], a0[6], ap[6];
        {
            const float* r = BPAD + im1 * 40 + j0;
            float4 v0 = *(const float4*)r, v1 = *(const float4*)(r + 4), v2 = *(const float4*)(r + 8);
            am[0] = le ? v1.x : v0.w; am[1] = v1.x; am[2] = v1.y; am[3] = v1.z; am[4] = v1.w;
            am[5] = re ? v1.w : v2.x;
        }
        {
            const float* r = BPAD + i * 40 + j0;
            float4 v0 = *(const float4*)r, v1 = *(const float4*)(r + 4), v2 = *(const float4*)(r + 8);
            a0[0] = le ? v1.x : v0.w; a0[1] = v1.x; a0[2] = v1.y; a0[3] = v1.z; a0[4] = v1.w;
            a0[5] = re ? v1.w : v2.x;
        }
        {
            const float* r = BPAD + ip1 * 40 + j0;
            float4 v0 = *(const float4*)r, v1 = *(const float4*)(r + 4), v2 = *(const float4*)(r + 8);
            ap[0] = le ? v1.x : v0.w; ap[1] = v1.x; ap[2] = v1.y; ap[3] = v1.z; ap[4] = v1.w;
            ap[5] = re ? v1.w : v2.x;
        }
        #pragma unroll
        for (int q = 0; q < 4; ++q) {
            float tm = am[q + 2] - am[q];
            float t0 = a0[q + 2] - a0[q];
            float tp = ap[q + 2] - ap[q];
            float jsob = (tm + 2.0f * t0) + tp;
            float um = ap[q] - am[q];
            float u0 = ap[q + 1] - am[q + 1];
            float up = ap[q + 2] - am[q + 2];
            float isob = (um + 2.0f * u0) + up;
            jsr[q] = jsob; isr[q] = isob;
            float m = sqrtf((isob * isob + jsob * jsob) + 1e-9f);
            mr[q] = m;
            MPAD[(i + 1) * MS + (j0 + q + 1)] = m;
        }
    }
    __syncthreads();   // B3

    // branchless NMS; nibble masks + shfl_xor OR over the 8-lane row octet
    {
        unsigned int ew = er[i];
        unsigned int hn = 0u, ln = 0u;
        #pragma unroll
        for (int q = 0; q < 4; ++q) {
            int j = j0 + q;
            float iv = isr[q], jv = jsr[q], m = mr[q];
            float ai = fabsf(iv), aj = fabsf(jv);
            bool same = (iv >= 0.0f && jv >= 0.0f) || (iv <= 0.0f && jv <= 0.0f);
            bool opp  = (iv <= 0.0f && jv >= 0.0f) || (iv >= 0.0f && jv <= 0.0f);
            bool age  = (ai >= aj), ale = (ai <= aj);
            int oct = (opp && age) ? 3 : (opp && ale) ? 2 : (same && ale) ? 1 : 0;
            float ais = ai > 0.0f ? ai : 1.0f;
            float ajs = aj > 0.0f ? aj : 1.0f;
            float num = (oct == 3 || oct == 0) ? aj : ai;
            float den = (oct == 3) ? ais : (oct == 0) ? (ai + 1e-9f) : ajs;
            float wq = num / den;
            float omw = 1.0f - wq;
            int p2i = (oct >= 2) ? -1 : 1;
            int p1i = (oct == 0) ? 1 : (oct == 3) ? -1 : 0;
            int p1j = (oct == 1 || oct == 2) ? 1 : 0;
            int base = (i + 1) * MS + (j + 1);
            float ipv = MPAD[base + p2i * MS + 1] * wq + MPAD[base + p1i * MS + p1j] * omw;
            float imv = MPAD[base - p2i * MS - 1] * wq + MPAD[base - p1i * MS - p1j] * omw;
            bool lm = (ipv <= m) && (imv <= m);
            bool eb = (ew >> j) & 1u;
            if (lm && eb && (m >= 0.2f)) hn |= (1u << j);
            if (lm && eb && (m >= 0.1f)) ln |= (1u << j);
        }
        #pragma unroll
        for (int mset = 1; mset < 8; mset <<= 1) {
            hn |= (unsigned int)__shfl_xor((int)hn, mset, 64);
            ln |= (unsigned int)__shfl_xor((int)ln, mset, 64);
        }
        if ((tid & 7) == 0) { hi32[i] = hn; lo32[i] = ln; }
    }
    __syncthreads();   // B4

    // hysteresis flood on ALL waves (redundant, identical result per wave)
    unsigned int cur;
    {
        unsigned int lw = (l < 32) ? lo32[l] : 0u;
        cur             = (l < 32) ? hi32[l] : 0u;
        for (;;) {
            unsigned int sp  = cur | (cur << 1) | (cur >> 1);
            unsigned int upv = (unsigned int)__shfl((int)sp, (l + 63) & 63, 64);
            if (l == 0) upv = 0u;
            unsigned int dnv = (unsigned int)__shfl((int)sp, (l + 1) & 63, 64);
            unsigned int nxt = (sp | upv | dnv) & lw;
            bool ch = (nxt != cur);
            cur = nxt;
            if (__ballot((int)ch) == 0ull) break;
        }
    }

    // output: row word via shfl from lane i of own wave; float4 store
    {
        unsigned int wd = (unsigned int)__shfl((int)cur, i, 64);
        float4 o;
        o.x = ((wd >> (j0    )) & 1u) ? 1.0f : -1.0f;
        o.y = ((wd >> (j0 + 1)) & 1u) ? 1.0f : -1.0f;
        o.z = ((wd >> (j0 + 2)) & 1u) ? 1.0f : -1.0f;
        o.w = ((wd >> (j0 + 3)) & 1u) ? 1.0f : -1.0f;
        ((float4*)(out + (size_t)b * NPIX))[tid] = o;
    }
}

extern "C" void kernel_launch(void* const* d_in, const int* in_sizes, int n_in,
                              void* d_out, int out_size, void* d_ws, size_t ws_size,
                              hipStream_t stream) {
    const float* x    = (const float*)d_in[0];
    const float* mask = (const float*)d_in[1];
    float* out        = (float*)d_out;
    double* ws_blrcp  = (double*)d_ws;                       // 1024 doubles
    unsigned int* ws_er = (unsigned int*)(ws_blrcp + NPIX);  // 32 u32
    float* ws_gk      = (float*)(ws_er + 32);                // 9 floats
    int Bn = in_sizes[0] / (3 * NPIX);

    hipLaunchKernelGGL(canny_pre, dim3(1), dim3(256), 0, stream, x, mask, ws_blrcp, ws_er, ws_gk);
    hipLaunchKernelGGL(canny_main, dim3(Bn), dim3(256), 0, stream, x, ws_blrcp, ws_er, ws_gk, out);
}